// Round 4
// baseline (3298.944 us; speedup 1.0000x reference)
//
#include <hip/hip_runtime.h>
#include <hip/hip_bf16.h>

// ViT forward, MI355X gfx950. Round 4: 256^2 8-wave double-buffered GEMM (T3 min-2-phase
// + T5 setprio) for QKV/FC1; 128-tile GEMM gains dbuf early-issue for FC2/O-proj/proj.

typedef __bf16 bf16;
typedef __bf16 bf16x8 __attribute__((ext_vector_type(8)));
typedef __bf16 bf16x4 __attribute__((ext_vector_type(4)));
typedef float  f32x4  __attribute__((ext_vector_type(4)));

typedef __attribute__((address_space(1))) const unsigned int gu32;
typedef __attribute__((address_space(3))) unsigned int lu32;

static __device__ __forceinline__ f32x4 mfma_bf16(bf16x8 a, bf16x8 b, f32x4 c) {
  return __builtin_amdgcn_mfma_f32_16x16x32_bf16(a, b, c, 0, 0, 0);
}
static __device__ __forceinline__ void gll16(const bf16* g, bf16* l) {
  __builtin_amdgcn_global_load_lds((gu32*)g, (lu32*)l, 16, 0, 0);
}

// ---------------- small setup kernels ----------------

__global__ __launch_bounds__(256) void f2b_k(const float* __restrict__ a, bf16* __restrict__ o, int n) {
  int i = blockIdx.x * 256 + threadIdx.x;
  if (i < n) o[i] = (bf16)a[i];
}

__global__ __launch_bounds__(256) void posenc_k(float* __restrict__ pos) {
  int l = blockIdx.x;
  for (int d = threadIdx.x; d < 768; d += 256) {
    int ieff = d & ~1;
    float ang = (float)l * expf(-(float)ieff * (9.210340371976184f / 768.0f)); // 10000^{-i/768}
    pos[l * 768 + d] = (d & 1) ? cosf(ang) : sinf(ang);
  }
}

// patches[t, c*256+i*16+j] = x[b, c, ph*16+i, pw*16+j],  t = b*196 + ph*14 + pw
__global__ __launch_bounds__(256) void patchify_k(const float* __restrict__ x, bf16* __restrict__ p) {
  int idx = blockIdx.x * 256 + threadIdx.x;     // 6272*768 exact
  int t = idx / 768, col = idx - t * 768;
  int b = t / 196, pp = t - b * 196;
  int ph = pp / 14, pw = pp - ph * 14;
  int c = col >> 8, r = col & 255, i = r >> 4, j = r & 15;
  p[idx] = (bf16)x[((b * 3 + c) * 224 + ph * 16 + i) * 224 + pw * 16 + j];
}

__global__ __launch_bounds__(256) void combine_k(float* __restrict__ h, const float* __restrict__ pos,
                                                 const float* __restrict__ cls) {
  int idx = blockIdx.x * 256 + threadIdx.x;     // 6304*768 exact
  int t = idx / 768, d = idx - t * 768;
  int l = t % 197;
  float p = pos[l * 768 + d];
  if (l == 0) h[idx] = cls[d] + p;
  else        h[idx] += p;
}

// LayerNorm over 768, one wave per row, 4 rows/block, bf16 out.
// PAD=1: output row index remapped t=b*197+l -> b*200+l (QKV-GEMM B operand layout).
template<int PAD>
__global__ __launch_bounds__(256) void ln4_k(const float* __restrict__ x, const float* __restrict__ g,
                                             const float* __restrict__ bb, bf16* __restrict__ y,
                                             int nrows, int instride) {
  const int wave = threadIdx.x >> 6, lane = threadIdx.x & 63;
  const int row = blockIdx.x * 4 + wave;
  if (row >= nrows) return;
  const float4* x4 = (const float4*)(x + (size_t)row * instride);
  float4 v0 = x4[lane], v1 = x4[lane + 64], v2 = x4[lane + 128];
  float s  = v0.x + v0.y + v0.z + v0.w + v1.x + v1.y + v1.z + v1.w + v2.x + v2.y + v2.z + v2.w;
  float s2 = v0.x*v0.x + v0.y*v0.y + v0.z*v0.z + v0.w*v0.w
           + v1.x*v1.x + v1.y*v1.y + v1.z*v1.z + v1.w*v1.w
           + v2.x*v2.x + v2.y*v2.y + v2.z*v2.z + v2.w*v2.w;
  #pragma unroll
  for (int o = 1; o < 64; o <<= 1) { s += __shfl_xor(s, o); s2 += __shfl_xor(s2, o); }
  float m = s * (1.0f / 768.0f);
  float inv = rsqrtf(s2 * (1.0f / 768.0f) - m * m + 1e-5f);
  int orow = row;
  if (PAD) { int bq = row / 197; orow = row + bq * 3; }
  bf16* yr = y + (size_t)orow * 768;
  const float4* g4 = (const float4*)g;
  const float4* b4 = (const float4*)bb;
  #pragma unroll
  for (int i = 0; i < 3; ++i) {
    int idx = lane + i * 64;
    float4 vv = (i == 0) ? v0 : (i == 1) ? v1 : v2;
    float4 gv = g4[idx], bv = b4[idx];
    bf16x4 o;
    o[0] = (bf16)((vv.x - m) * inv * gv.x + bv.x);
    o[1] = (bf16)((vv.y - m) * inv * gv.y + bv.y);
    o[2] = (bf16)((vv.z - m) * inv * gv.z + bv.z);
    o[3] = (bf16)((vv.w - m) * inv * gv.w + bv.w);
    *(bf16x4*)(yr + idx * 4) = o;
  }
}

// ---------------- 128-tile NT GEMM, double-buffered early-issue ----------------
// C[M,N] = A[M,K] * B[N,K]^T. 128xBN tile, BK=64, 4 waves.
// EPI: 0=PROJ (h row remap, fp32)  2=ACCUM (outF[t*768+col]+=)
//      4=TANH (bf16, stride 768)   5=GUARDED fp32 store (stride ldc, col<N)
template<int BN, int EPI>
__global__ __launch_bounds__(256) void gemm2(
    const bf16* __restrict__ A, const bf16* __restrict__ B,
    int M, int N, int K, int ldc, const float* __restrict__ bias,
    float* __restrict__ outF, bf16* __restrict__ outB)
{
  constexpr int WN = (BN == 128) ? 64 : 32;
  constexpr int NI = WN / 16;
  constexpr int NB = BN / 32;
  __shared__ alignas(16) bf16 As[2][128 * 64];
  __shared__ alignas(16) bf16 Bs[2][BN * 64];
  const int tid = threadIdx.x;
  const int lane = tid & 63, wave = tid >> 6;
  const int wr = wave >> 1, wc = wave & 1;
  const int lrow = lane & 15, lgrp = lane >> 4;
  const int row0 = blockIdx.x * 128, col0 = blockIdx.y * BN;

  f32x4 acc[4][NI] = {};
  const bf16* Agb = A + (size_t)row0 * K;
  const bf16* Bgb = B + (size_t)col0 * K;
  const int srow = lane >> 3, schunk = lane & 7;
  const int nk = K >> 6;

  // prologue: stage tile 0 -> buf 0
  #pragma unroll
  for (int i = 0; i < 4; ++i) {
    int rr = (wave * 4 + i) * 8 + srow;
    int g = schunk ^ (rr & 7);
    gll16(Agb + (size_t)rr * K + g * 8, As[0] + (wave * 4 + i) * 512);
  }
  #pragma unroll
  for (int i = 0; i < NB; ++i) {
    int rr = (wave * NB + i) * 8 + srow;
    int g = schunk ^ (rr & 7);
    gll16(Bgb + (size_t)rr * K + g * 8, Bs[0] + (wave * NB + i) * 512);
  }
  __syncthreads();

  int cur = 0;
  for (int kt = 0; kt < nk; ++kt) {
    if (kt + 1 < nk) {                   // early-issue next tile into buf^1
      const bf16* Ag = Agb + (kt + 1) * 64;
      const bf16* Bg = Bgb + (kt + 1) * 64;
      bf16* Ad = As[cur ^ 1]; bf16* Bd = Bs[cur ^ 1];
      #pragma unroll
      for (int i = 0; i < 4; ++i) {
        int rr = (wave * 4 + i) * 8 + srow;
        int g = schunk ^ (rr & 7);
        gll16(Ag + (size_t)rr * K + g * 8, Ad + (wave * 4 + i) * 512);
      }
      #pragma unroll
      for (int i = 0; i < NB; ++i) {
        int rr = (wave * NB + i) * 8 + srow;
        int g = schunk ^ (rr & 7);
        gll16(Bg + (size_t)rr * K + g * 8, Bd + (wave * NB + i) * 512);
      }
    }
    const bf16* Ac = As[cur]; const bf16* Bc = Bs[cur];
    #pragma unroll
    for (int kk = 0; kk < 2; ++kk) {
      bf16x8 af[4], bfr[NI];
      #pragma unroll
      for (int mi = 0; mi < 4; ++mi) {
        int r = wr * 64 + mi * 16 + lrow;
        af[mi] = *(const bf16x8*)(Ac + r * 64 + (((kk * 4 + lgrp) ^ (r & 7)) << 3));
      }
      #pragma unroll
      for (int ni = 0; ni < NI; ++ni) {
        int r = wc * WN + ni * 16 + lrow;
        bfr[ni] = *(const bf16x8*)(Bc + r * 64 + (((kk * 4 + lgrp) ^ (r & 7)) << 3));
      }
      __builtin_amdgcn_s_setprio(1);
      #pragma unroll
      for (int mi = 0; mi < 4; ++mi)
        #pragma unroll
        for (int ni = 0; ni < NI; ++ni)
          acc[mi][ni] = mfma_bf16(af[mi], bfr[ni], acc[mi][ni]);
      __builtin_amdgcn_s_setprio(0);
    }
    __syncthreads();                     // drain vmcnt + barrier (tile boundary)
    cur ^= 1;
  }

  // epilogue: C frag layout col = lane&15, row = (lane>>4)*4 + j
  #pragma unroll
  for (int ni = 0; ni < NI; ++ni) {
    const int col = col0 + wc * WN + ni * 16 + lrow;
    float bs = (EPI == 5) ? ((col < N) ? bias[col] : 0.0f) : bias[col];
    #pragma unroll
    for (int mi = 0; mi < 4; ++mi) {
      const int rbase = row0 + wr * 64 + mi * 16 + (lgrp << 2);
      #pragma unroll
      for (int j = 0; j < 4; ++j) {
        const int t = rbase + j;
        if (t >= M) continue;
        float val = acc[mi][ni][j] + bs;
        if (EPI == 0) {
          int b = t / 196, p = t - b * 196;
          outF[((size_t)(b * 197 + 1 + p)) * 768 + col] = val;
        } else if (EPI == 2) {
          outF[(size_t)t * 768 + col] += val;
        } else if (EPI == 4) {
          outB[(size_t)t * 768 + col] = (bf16)tanhf(val);
        } else {
          if (col < N) outF[(size_t)t * ldc + col] = val;
        }
      }
    }
  }
}

// ---------------- 256-tile NT GEMM, 8 waves, dbuf early-issue (T3+T5) ----------------
// EPI: 1=QKVT (bf16, bias by ROW, rows<768 *0.125, stride ldc)
//      3=FC1 gelu (bf16, stride 3072)
template<int EPI>
__global__ __launch_bounds__(512, 2) void gemm3(
    const bf16* __restrict__ A, const bf16* __restrict__ B,
    int M, int N, int K, int ldc, const float* __restrict__ bias,
    bf16* __restrict__ outB)
{
  __shared__ alignas(16) bf16 As[2][256 * 64];   // 128 KiB total
  __shared__ alignas(16) bf16 Bs[2][256 * 64];
  const int tid = threadIdx.x;
  const int lane = tid & 63, wave = tid >> 6;
  const int wm = wave >> 2, wn = wave & 3;       // 2(M) x 4(N) wave grid
  const int lrow = lane & 15, lgrp = lane >> 4;
  const int row0 = blockIdx.x * 256, col0 = blockIdx.y * 256;

  f32x4 acc[8][4] = {};
  const bf16* Agb = A + (size_t)row0 * K;
  const bf16* Bgb = B + (size_t)col0 * K;
  const int srow = lane >> 3, schunk = lane & 7;
  const int nk = K >> 6;

  // prologue: stage tile 0 -> buf 0 (8 waves x 4 shots x 8 rows = 256 rows each of A,B)
  #pragma unroll
  for (int i = 0; i < 4; ++i) {
    int rr = (wave * 4 + i) * 8 + srow;
    int g = schunk ^ (rr & 7);
    gll16(Agb + (size_t)rr * K + g * 8, As[0] + (wave * 4 + i) * 512);
    gll16(Bgb + (size_t)rr * K + g * 8, Bs[0] + (wave * 4 + i) * 512);
  }
  __syncthreads();

  int cur = 0;
  for (int kt = 0; kt < nk; ++kt) {
    if (kt + 1 < nk) {                   // early-issue next K-tile into buf^1
      const bf16* Ag = Agb + (kt + 1) * 64;
      const bf16* Bg = Bgb + (kt + 1) * 64;
      bf16* Ad = As[cur ^ 1]; bf16* Bd = Bs[cur ^ 1];
      #pragma unroll
      for (int i = 0; i < 4; ++i) {
        int rr = (wave * 4 + i) * 8 + srow;
        int g = schunk ^ (rr & 7);
        gll16(Ag + (size_t)rr * K + g * 8, Ad + (wave * 4 + i) * 512);
        gll16(Bg + (size_t)rr * K + g * 8, Bd + (wave * 4 + i) * 512);
      }
    }
    const bf16* Ac = As[cur]; const bf16* Bc = Bs[cur];
    #pragma unroll
    for (int kk = 0; kk < 2; ++kk) {
      bf16x8 af[4], bfr[4];
      #pragma unroll
      for (int ni = 0; ni < 4; ++ni) {
        int r = wn * 64 + ni * 16 + lrow;
        bfr[ni] = *(const bf16x8*)(Bc + r * 64 + (((kk * 4 + lgrp) ^ (r & 7)) << 3));
      }
      #pragma unroll
      for (int mi = 0; mi < 4; ++mi) {
        int r = wm * 128 + mi * 16 + lrow;
        af[mi] = *(const bf16x8*)(Ac + r * 64 + (((kk * 4 + lgrp) ^ (r & 7)) << 3));
      }
      __builtin_amdgcn_s_setprio(1);
      #pragma unroll
      for (int mi = 0; mi < 4; ++mi)
        #pragma unroll
        for (int ni = 0; ni < 4; ++ni)
          acc[mi][ni] = mfma_bf16(af[mi], bfr[ni], acc[mi][ni]);
      __builtin_amdgcn_s_setprio(0);
      #pragma unroll
      for (int mi = 0; mi < 4; ++mi) {
        int r = wm * 128 + 64 + mi * 16 + lrow;
        af[mi] = *(const bf16x8*)(Ac + r * 64 + (((kk * 4 + lgrp) ^ (r & 7)) << 3));
      }
      __builtin_amdgcn_s_setprio(1);
      #pragma unroll
      for (int mi = 0; mi < 4; ++mi)
        #pragma unroll
        for (int ni = 0; ni < 4; ++ni)
          acc[4 + mi][ni] = mfma_bf16(af[mi], bfr[ni], acc[4 + mi][ni]);
      __builtin_amdgcn_s_setprio(0);
    }
    __syncthreads();
    cur ^= 1;
  }

  // epilogue
  #pragma unroll
  for (int ni = 0; ni < 4; ++ni) {
    const int col = col0 + wn * 64 + ni * 16 + lrow;
    float bs = (EPI == 3) ? bias[col] : 0.0f;
    #pragma unroll
    for (int mi = 0; mi < 8; ++mi) {
      const int rbase = row0 + wm * 128 + mi * 16 + (lgrp << 2);
      #pragma unroll
      for (int j = 0; j < 4; ++j) {
        const int t = rbase + j;
        if (EPI == 1) {
          float val = acc[mi][ni][j] + bias[t];
          if (t < 768) val *= 0.125f;
          outB[(size_t)t * ldc + col] = (bf16)val;
        } else {
          if (t >= M) continue;
          float val = acc[mi][ni][j] + bs;
          outB[(size_t)t * 3072 + col] = (bf16)(0.5f * val * (1.0f + erff(val * 0.70710678118654752f)));
        }
      }
    }
  }
}

// ---------------- attention: one block per (b, head), 8 waves ----------------
// Ct: QKV^T [2304][6400] bf16, cols = b*200 + l (rows n = comp*768 + d*12 + h; Q pre-scaled 1/8).
// O: [6304][768] bf16 (t = b*197 + l).
__global__ __launch_bounds__(512) void attn_k(const bf16* __restrict__ Ct, bf16* __restrict__ O) {
  __shared__ alignas(16) bf16 Ks[208 * 64];       // [l][d] XOR-swizzled
  __shared__ alignas(16) bf16 Qs[208 * 64];       // [l][d] XOR-swizzled
  __shared__ alignas(16) bf16 Vs[64 * 232];       // [d][l] pad 232, cols 197..231 zeroed
  __shared__ alignas(16) bf16 Ps[8][16 * 232];    // per-wave P tile
  const int bh = blockIdx.x;
  const int b = bh / 12, hh = bh - b * 12;
  const int tid = threadIdx.x, lane = tid & 63, wave = tid >> 6;
  const int lrow = lane & 15, lgrp = lane >> 4;
  const size_t tc0 = (size_t)b * 200;

  for (int task = tid; task < 1600; task += 512) {
    int d = task / 25, lc = task - d * 25;
    int l0 = lc * 8;
    const size_t cb = tc0 + l0;
    bf16x8 qv = *(const bf16x8*)(Ct + ((size_t)(d * 12 + hh)) * 6400 + cb);
    bf16x8 kv = *(const bf16x8*)(Ct + ((size_t)(768 + d * 12 + hh)) * 6400 + cb);
    bf16x8 vv = *(const bf16x8*)(Ct + ((size_t)(1536 + d * 12 + hh)) * 6400 + cb);
    #pragma unroll
    for (int e = 0; e < 8; ++e) {
      int l = l0 + e;
      int sw = ((((d >> 3) ^ (l & 7)) << 3) | (d & 7));
      Ks[l * 64 + sw] = kv[e];
      Qs[l * 64 + sw] = qv[e];
    }
    *(bf16x8*)(Vs + d * 232 + l0) = vv;
  }
  for (int q = tid; q < 64 * 35; q += 512) {      // zero V cols 197..231
    int d = q / 35, c = 197 + (q - d * 35);
    Vs[d * 232 + c] = (bf16)0.0f;
  }
  __syncthreads();

  for (int rt = wave; rt < 13; rt += 8) {
    const int r = rt * 16 + lrow;
    bf16x8 a0 = *(const bf16x8*)(Qs + r * 64 + ((lgrp ^ (r & 7)) << 3));
    bf16x8 a1 = *(const bf16x8*)(Qs + r * 64 + (((4 + lgrp) ^ (r & 7)) << 3));
    f32x4 sacc[13];
    #pragma unroll
    for (int ct = 0; ct < 13; ++ct) {
      const int kr = ct * 16 + lrow;
      bf16x8 b0 = *(const bf16x8*)(Ks + kr * 64 + ((lgrp ^ (kr & 7)) << 3));
      bf16x8 b1 = *(const bf16x8*)(Ks + kr * 64 + (((4 + lgrp) ^ (kr & 7)) << 3));
      f32x4 s = {};
      s = mfma_bf16(a0, b0, s);
      s = mfma_bf16(a1, b1, s);
      sacc[ct] = s;
    }
    bf16* Pw = Ps[wave];
    float inv4[4];
    #pragma unroll
    for (int j = 0; j < 4; ++j) {
      const int prow = (lgrp << 2) + j;
      float mx = -3.0e38f;
      #pragma unroll
      for (int ct = 0; ct < 13; ++ct) {
        int c = ct * 16 + lrow;
        if (c < 197) mx = fmaxf(mx, sacc[ct][j]);
      }
      #pragma unroll
      for (int o = 1; o < 16; o <<= 1) mx = fmaxf(mx, __shfl_xor(mx, o));
      float sum = 0.0f;
      #pragma unroll
      for (int ct = 0; ct < 13; ++ct) {
        int c = ct * 16 + lrow;
        float p = (c < 197) ? __expf(sacc[ct][j] - mx) : 0.0f;
        sum += p;
        Pw[prow * 232 + c] = (bf16)p;
      }
      #pragma unroll
      for (int o = 1; o < 16; o <<= 1) sum += __shfl_xor(sum, o);
      inv4[j] = 1.0f / sum;
      Pw[prow * 232 + 208 + lrow] = (bf16)0.0f;   // zero P cols 208..223
    }
    f32x4 oacc[4] = {};
    #pragma unroll
    for (int mc = 0; mc < 7; ++mc) {              // K-dim 224
      bf16x8 pa = *(const bf16x8*)(Pw + lrow * 232 + mc * 32 + (lgrp << 3));
      #pragma unroll
      for (int n2 = 0; n2 < 4; ++n2) {
        bf16x8 vb = *(const bf16x8*)(Vs + (n2 * 16 + lrow) * 232 + mc * 32 + (lgrp << 3));
        oacc[n2] = mfma_bf16(pa, vb, oacc[n2]);
      }
    }
    #pragma unroll
    for (int n2 = 0; n2 < 4; ++n2) {
      const int d = n2 * 16 + lrow;
      #pragma unroll
      for (int j = 0; j < 4; ++j) {
        const int qrow = rt * 16 + (lgrp << 2) + j;
        if (qrow < 197)
          O[((size_t)b * 197 + qrow) * 768 + hh * 64 + d] = (bf16)(oacc[n2][j] * inv4[j]);
      }
    }
  }
}

// ---------------- driver ----------------

extern "C" void kernel_launch(void* const* d_in, const int* in_sizes, int n_in,
                              void* d_out, int out_size, void* d_ws, size_t ws_size,
                              hipStream_t stream) {
  const float* x      = (const float*)d_in[0];
  const float* w_proj = (const float*)d_in[1];
  const float* b_proj = (const float*)d_in[2];
  const float* cls    = (const float*)d_in[3];
  const float* ln1g   = (const float*)d_in[4];
  const float* ln1b   = (const float*)d_in[5];
  const float* w_qkv  = (const float*)d_in[6];
  const float* b_qkv  = (const float*)d_in[7];
  const float* w_o    = (const float*)d_in[8];
  const float* b_o    = (const float*)d_in[9];
  const float* ln2g   = (const float*)d_in[10];
  const float* ln2b   = (const float*)d_in[11];
  const float* w_fc1  = (const float*)d_in[12];
  const float* b_fc1  = (const float*)d_in[13];
  const float* w_fc2  = (const float*)d_in[14];
  const float* b_fc2  = (const float*)d_in[15];
  const float* lnfg   = (const float*)d_in[16];
  const float* lnfb   = (const float*)d_in[17];
  const float* w_h    = (const float*)d_in[18];
  const float* b_h    = (const float*)d_in[19];
  const float* w_c    = (const float*)d_in[20];
  const float* b_c    = (const float*)d_in[21];
  float* out = (float*)d_out;

  uint8_t* ws = (uint8_t*)d_ws;
  size_t off = 0;
  auto alloc = [&](size_t bytes) -> void* {
    void* p = ws + off; off += (bytes + 255) & ~(size_t)255; return p;
  };
  float* h    = (float*)alloc(6400ull * 768 * 4);   // residual fp32 (t = b*197+l)
  bf16*  ybf  = (bf16*) alloc(6400ull * 768 * 2);   // LN out bf16 (plain OR b*200+l padded)
  bf16*  ct   = (bf16*) alloc(2304ull * 6400 * 2);  // QKV^T, cols b*200+l
  bf16*  ob   = (bf16*) alloc(6400ull * 768 * 2);   // attention out bf16
  bf16*  f1   = (bf16*) alloc(6400ull * 3072 * 2);  // FC1 out bf16
  float* pos  = (float*)alloc(197ull * 768 * 4);
  bf16* wprojB = (bf16*)alloc(768ull * 768 * 2);
  bf16* wqkvB  = (bf16*)alloc(2304ull * 768 * 2);
  bf16* woB    = (bf16*)alloc(768ull * 768 * 2);
  bf16* wfc1B  = (bf16*)alloc(3072ull * 768 * 2);
  bf16* wfc2B  = (bf16*)alloc(768ull * 3072 * 2);
  bf16* whB    = (bf16*)alloc(768ull * 768 * 2);
  bf16* wcB    = (bf16*)alloc(1024ull * 768 * 2);   // rows 1000..1023 poison (finite)
  bf16* repB   = (bf16*)alloc(128ull * 768 * 2);    // rows 32..127 poison
  bf16* hidB   = (bf16*)alloc(128ull * 768 * 2);
  bf16* patches = f1;   // alias: patches dead before FC1 first writes f1

  f2b_k<<<(768 * 768 + 255) / 256, 256, 0, stream>>>(w_proj, wprojB, 768 * 768);
  f2b_k<<<(2304 * 768 + 255) / 256, 256, 0, stream>>>(w_qkv, wqkvB, 2304 * 768);
  f2b_k<<<(768 * 768 + 255) / 256, 256, 0, stream>>>(w_o, woB, 768 * 768);
  f2b_k<<<(3072 * 768 + 255) / 256, 256, 0, stream>>>(w_fc1, wfc1B, 3072 * 768);
  f2b_k<<<(768 * 3072 + 255) / 256, 256, 0, stream>>>(w_fc2, wfc2B, 768 * 3072);
  f2b_k<<<(768 * 768 + 255) / 256, 256, 0, stream>>>(w_h, whB, 768 * 768);
  f2b_k<<<(1000 * 768 + 255) / 256, 256, 0, stream>>>(w_c, wcB, 1000 * 768);
  posenc_k<<<197, 256, 0, stream>>>(pos);
  patchify_k<<<6272 * 768 / 256, 256, 0, stream>>>(x, patches);
  gemm2<64, 0><<<dim3(49, 12), 256, 0, stream>>>(patches, wprojB, 6272, 768, 768, 768, b_proj, h, nullptr);
  combine_k<<<6304 * 768 / 256, 256, 0, stream>>>(h, pos, cls);

  for (int layer = 0; layer < 12; ++layer) {
    ln4_k<1><<<1576, 256, 0, stream>>>(h, ln1g, ln1b, ybf, 6304, 768);
    // QKV^T: A = w_qkv [2304][768], B = ybf(padded rows, 6400) -> Ct [2304][6400]
    gemm3<1><<<dim3(9, 25), 512, 0, stream>>>(wqkvB, ybf, 2304, 6400, 768, 6400, b_qkv, ct);
    attn_k<<<384, 512, 0, stream>>>(ct, ob);
    gemm2<64, 2><<<dim3(50, 12), 256, 0, stream>>>(ob, woB, 6304, 768, 768, 768, b_o, h, nullptr);
    ln4_k<0><<<1576, 256, 0, stream>>>(h, ln2g, ln2b, ybf, 6304, 768);
    gemm3<3><<<dim3(25, 12), 512, 0, stream>>>(ybf, wfc1B, 6304, 3072, 768, 3072, b_fc1, f1);
    gemm2<64, 2><<<dim3(50, 12), 256, 0, stream>>>(f1, wfc2B, 6304, 768, 3072, 768, b_fc2, h, nullptr);
  }

  ln4_k<0><<<8, 256, 0, stream>>>(h, lnfg, lnfb, repB, 32, 197 * 768);
  gemm2<64, 4><<<dim3(1, 12), 256, 0, stream>>>(repB, whB, 32, 768, 768, 768, b_h, nullptr, hidB);
  gemm2<64, 5><<<dim3(1, 16), 256, 0, stream>>>(hidB, wcB, 32, 1000, 768, 1000, b_c, out, nullptr);
}

// Round 5
// 2962.161 us; speedup vs baseline: 1.1137x; 1.1137x over previous
//
#include <hip/hip_runtime.h>
#include <hip/hip_bf16.h>

// ViT forward, MI355X gfx950. Round 5: all GEMMs on the double-buffered early-issue
// 128-tile kernel (2-3 blocks/CU so barrier drains are covered by sibling blocks).
// gemm3 (256^2, 1 block/CU) reverted: grid quantization + no co-resident overlap.

typedef __bf16 bf16;
typedef __bf16 bf16x8 __attribute__((ext_vector_type(8)));
typedef __bf16 bf16x4 __attribute__((ext_vector_type(4)));
typedef float  f32x4  __attribute__((ext_vector_type(4)));

typedef __attribute__((address_space(1))) const unsigned int gu32;
typedef __attribute__((address_space(3))) unsigned int lu32;

static __device__ __forceinline__ f32x4 mfma_bf16(bf16x8 a, bf16x8 b, f32x4 c) {
  return __builtin_amdgcn_mfma_f32_16x16x32_bf16(a, b, c, 0, 0, 0);
}
static __device__ __forceinline__ void gll16(const bf16* g, bf16* l) {
  __builtin_amdgcn_global_load_lds((gu32*)g, (lu32*)l, 16, 0, 0);
}

// ---------------- small setup kernels ----------------

__global__ __launch_bounds__(256) void f2b_k(const float* __restrict__ a, bf16* __restrict__ o, int n) {
  int i = blockIdx.x * 256 + threadIdx.x;
  if (i < n) o[i] = (bf16)a[i];
}

__global__ __launch_bounds__(256) void posenc_k(float* __restrict__ pos) {
  int l = blockIdx.x;
  for (int d = threadIdx.x; d < 768; d += 256) {
    int ieff = d & ~1;
    float ang = (float)l * expf(-(float)ieff * (9.210340371976184f / 768.0f)); // 10000^{-i/768}
    pos[l * 768 + d] = (d & 1) ? cosf(ang) : sinf(ang);
  }
}

// patches[t, c*256+i*16+j] = x[b, c, ph*16+i, pw*16+j],  t = b*196 + ph*14 + pw
__global__ __launch_bounds__(256) void patchify_k(const float* __restrict__ x, bf16* __restrict__ p) {
  int idx = blockIdx.x * 256 + threadIdx.x;     // 6272*768 exact
  int t = idx / 768, col = idx - t * 768;
  int b = t / 196, pp = t - b * 196;
  int ph = pp / 14, pw = pp - ph * 14;
  int c = col >> 8, r = col & 255, i = r >> 4, j = r & 15;
  p[idx] = (bf16)x[((b * 3 + c) * 224 + ph * 16 + i) * 224 + pw * 16 + j];
}

__global__ __launch_bounds__(256) void combine_k(float* __restrict__ h, const float* __restrict__ pos,
                                                 const float* __restrict__ cls) {
  int idx = blockIdx.x * 256 + threadIdx.x;     // 6304*768 exact
  int t = idx / 768, d = idx - t * 768;
  int l = t % 197;
  float p = pos[l * 768 + d];
  if (l == 0) h[idx] = cls[d] + p;
  else        h[idx] += p;
}

// LayerNorm over 768, one wave per row, 4 rows/block, bf16 out.
// PAD=1: output row index remapped t=b*197+l -> b*200+l (QKV-GEMM B operand layout).
template<int PAD>
__global__ __launch_bounds__(256) void ln4_k(const float* __restrict__ x, const float* __restrict__ g,
                                             const float* __restrict__ bb, bf16* __restrict__ y,
                                             int nrows, int instride) {
  const int wave = threadIdx.x >> 6, lane = threadIdx.x & 63;
  const int row = blockIdx.x * 4 + wave;
  if (row >= nrows) return;
  const float4* x4 = (const float4*)(x + (size_t)row * instride);
  float4 v0 = x4[lane], v1 = x4[lane + 64], v2 = x4[lane + 128];
  float s  = v0.x + v0.y + v0.z + v0.w + v1.x + v1.y + v1.z + v1.w + v2.x + v2.y + v2.z + v2.w;
  float s2 = v0.x*v0.x + v0.y*v0.y + v0.z*v0.z + v0.w*v0.w
           + v1.x*v1.x + v1.y*v1.y + v1.z*v1.z + v1.w*v1.w
           + v2.x*v2.x + v2.y*v2.y + v2.z*v2.z + v2.w*v2.w;
  #pragma unroll
  for (int o = 1; o < 64; o <<= 1) { s += __shfl_xor(s, o); s2 += __shfl_xor(s2, o); }
  float m = s * (1.0f / 768.0f);
  float inv = rsqrtf(s2 * (1.0f / 768.0f) - m * m + 1e-5f);
  int orow = row;
  if (PAD) { int bq = row / 197; orow = row + bq * 3; }
  bf16* yr = y + (size_t)orow * 768;
  const float4* g4 = (const float4*)g;
  const float4* b4 = (const float4*)bb;
  #pragma unroll
  for (int i = 0; i < 3; ++i) {
    int idx = lane + i * 64;
    float4 vv = (i == 0) ? v0 : (i == 1) ? v1 : v2;
    float4 gv = g4[idx], bv = b4[idx];
    bf16x4 o;
    o[0] = (bf16)((vv.x - m) * inv * gv.x + bv.x);
    o[1] = (bf16)((vv.y - m) * inv * gv.y + bv.y);
    o[2] = (bf16)((vv.z - m) * inv * gv.z + bv.z);
    o[3] = (bf16)((vv.w - m) * inv * gv.w + bv.w);
    *(bf16x4*)(yr + idx * 4) = o;
  }
}

// ---------------- 128-tile NT GEMM, double-buffered early-issue ----------------
// C[M,N] = A[M,K] * B[N,K]^T. 128xBN tile, BK=64, 4 waves (2x2).
// EPI: 0=PROJ (h row remap, fp32)  1=QKVT (bf16, bias by ROW, rows<768 *0.125, stride ldc)
//      2=ACCUM (outF[t*768+col]+=) 3=FC1 gelu (bf16, stride 3072)
//      4=TANH (bf16, stride 768)   5=GUARDED fp32 store (stride ldc, col<N)
template<int BN, int EPI>
__global__ __launch_bounds__(256) void gemm2(
    const bf16* __restrict__ A, const bf16* __restrict__ B,
    int M, int N, int K, int ldc, const float* __restrict__ bias,
    float* __restrict__ outF, bf16* __restrict__ outB)
{
  constexpr int WN = (BN == 128) ? 64 : 32;
  constexpr int NI = WN / 16;
  constexpr int NB = BN / 32;
  __shared__ alignas(16) bf16 As[2][128 * 64];
  __shared__ alignas(16) bf16 Bs[2][BN * 64];
  const int tid = threadIdx.x;
  const int lane = tid & 63, wave = tid >> 6;
  const int wr = wave >> 1, wc = wave & 1;
  const int lrow = lane & 15, lgrp = lane >> 4;
  const int row0 = blockIdx.x * 128, col0 = blockIdx.y * BN;

  f32x4 acc[4][NI] = {};
  const bf16* Agb = A + (size_t)row0 * K;
  const bf16* Bgb = B + (size_t)col0 * K;
  const int srow = lane >> 3, schunk = lane & 7;
  const int nk = K >> 6;

  // prologue: stage tile 0 -> buf 0
  #pragma unroll
  for (int i = 0; i < 4; ++i) {
    int rr = (wave * 4 + i) * 8 + srow;
    int g = schunk ^ (rr & 7);
    gll16(Agb + (size_t)rr * K + g * 8, As[0] + (wave * 4 + i) * 512);
  }
  #pragma unroll
  for (int i = 0; i < NB; ++i) {
    int rr = (wave * NB + i) * 8 + srow;
    int g = schunk ^ (rr & 7);
    gll16(Bgb + (size_t)rr * K + g * 8, Bs[0] + (wave * NB + i) * 512);
  }
  __syncthreads();

  int cur = 0;
  for (int kt = 0; kt < nk; ++kt) {
    if (kt + 1 < nk) {                   // early-issue next tile into buf^1
      const bf16* Ag = Agb + (kt + 1) * 64;
      const bf16* Bg = Bgb + (kt + 1) * 64;
      bf16* Ad = As[cur ^ 1]; bf16* Bd = Bs[cur ^ 1];
      #pragma unroll
      for (int i = 0; i < 4; ++i) {
        int rr = (wave * 4 + i) * 8 + srow;
        int g = schunk ^ (rr & 7);
        gll16(Ag + (size_t)rr * K + g * 8, Ad + (wave * 4 + i) * 512);
      }
      #pragma unroll
      for (int i = 0; i < NB; ++i) {
        int rr = (wave * NB + i) * 8 + srow;
        int g = schunk ^ (rr & 7);
        gll16(Bg + (size_t)rr * K + g * 8, Bd + (wave * NB + i) * 512);
      }
    }
    const bf16* Ac = As[cur]; const bf16* Bc = Bs[cur];
    #pragma unroll
    for (int kk = 0; kk < 2; ++kk) {
      bf16x8 af[4], bfr[NI];
      #pragma unroll
      for (int mi = 0; mi < 4; ++mi) {
        int r = wr * 64 + mi * 16 + lrow;
        af[mi] = *(const bf16x8*)(Ac + r * 64 + (((kk * 4 + lgrp) ^ (r & 7)) << 3));
      }
      #pragma unroll
      for (int ni = 0; ni < NI; ++ni) {
        int r = wc * WN + ni * 16 + lrow;
        bfr[ni] = *(const bf16x8*)(Bc + r * 64 + (((kk * 4 + lgrp) ^ (r & 7)) << 3));
      }
      __builtin_amdgcn_s_setprio(1);
      #pragma unroll
      for (int mi = 0; mi < 4; ++mi)
        #pragma unroll
        for (int ni = 0; ni < NI; ++ni)
          acc[mi][ni] = mfma_bf16(af[mi], bfr[ni], acc[mi][ni]);
      __builtin_amdgcn_s_setprio(0);
    }
    __syncthreads();                     // drain vmcnt + barrier (tile boundary)
    cur ^= 1;
  }

  // epilogue: C frag layout col = lane&15, row = (lane>>4)*4 + j
  #pragma unroll
  for (int ni = 0; ni < NI; ++ni) {
    const int col = col0 + wc * WN + ni * 16 + lrow;
    float bs = 0.0f;
    if (EPI != 1) {
      if (EPI == 5) bs = (col < N) ? bias[col] : 0.0f;
      else          bs = bias[col];
    }
    #pragma unroll
    for (int mi = 0; mi < 4; ++mi) {
      const int rbase = row0 + wr * 64 + mi * 16 + (lgrp << 2);
      #pragma unroll
      for (int j = 0; j < 4; ++j) {
        const int t = rbase + j;
        if (EPI == 1) {
          float val = acc[mi][ni][j] + bias[t];
          if (t < 768) val *= 0.125f;
          outB[(size_t)t * ldc + col] = (bf16)val;
        } else {
          if (t >= M) continue;
          float val = acc[mi][ni][j] + bs;
          if (EPI == 0) {
            int b = t / 196, p = t - b * 196;
            outF[((size_t)(b * 197 + 1 + p)) * 768 + col] = val;
          } else if (EPI == 2) {
            outF[(size_t)t * 768 + col] += val;
          } else if (EPI == 3) {
            outB[(size_t)t * 3072 + col] = (bf16)(0.5f * val * (1.0f + erff(val * 0.70710678118654752f)));
          } else if (EPI == 4) {
            outB[(size_t)t * 768 + col] = (bf16)tanhf(val);
          } else {
            if (col < N) outF[(size_t)t * ldc + col] = val;
          }
        }
      }
    }
  }
}

// ---------------- attention: one block per (b, head), 8 waves ----------------
// Ct: QKV^T [2304][6400] bf16, cols = b*200 + l (rows n = comp*768 + d*12 + h; Q pre-scaled 1/8).
// O: [6304][768] bf16 (t = b*197 + l).
__global__ __launch_bounds__(512) void attn_k(const bf16* __restrict__ Ct, bf16* __restrict__ O) {
  __shared__ alignas(16) bf16 Ks[208 * 64];       // [l][d] XOR-swizzled
  __shared__ alignas(16) bf16 Qs[208 * 64];       // [l][d] XOR-swizzled
  __shared__ alignas(16) bf16 Vs[64 * 232];       // [d][l] pad 232, cols 197..231 zeroed
  __shared__ alignas(16) bf16 Ps[8][16 * 232];    // per-wave P tile
  const int bh = blockIdx.x;
  const int b = bh / 12, hh = bh - b * 12;
  const int tid = threadIdx.x, lane = tid & 63, wave = tid >> 6;
  const int lrow = lane & 15, lgrp = lane >> 4;
  const size_t tc0 = (size_t)b * 200;

  for (int task = tid; task < 1600; task += 512) {
    int d = task / 25, lc = task - d * 25;
    int l0 = lc * 8;
    const size_t cb = tc0 + l0;
    bf16x8 qv = *(const bf16x8*)(Ct + ((size_t)(d * 12 + hh)) * 6400 + cb);
    bf16x8 kv = *(const bf16x8*)(Ct + ((size_t)(768 + d * 12 + hh)) * 6400 + cb);
    bf16x8 vv = *(const bf16x8*)(Ct + ((size_t)(1536 + d * 12 + hh)) * 6400 + cb);
    #pragma unroll
    for (int e = 0; e < 8; ++e) {
      int l = l0 + e;
      int sw = ((((d >> 3) ^ (l & 7)) << 3) | (d & 7));
      Ks[l * 64 + sw] = kv[e];
      Qs[l * 64 + sw] = qv[e];
    }
    *(bf16x8*)(Vs + d * 232 + l0) = vv;
  }
  for (int q = tid; q < 64 * 35; q += 512) {      // zero V cols 197..231
    int d = q / 35, c = 197 + (q - d * 35);
    Vs[d * 232 + c] = (bf16)0.0f;
  }
  __syncthreads();

  for (int rt = wave; rt < 13; rt += 8) {
    const int r = rt * 16 + lrow;
    bf16x8 a0 = *(const bf16x8*)(Qs + r * 64 + ((lgrp ^ (r & 7)) << 3));
    bf16x8 a1 = *(const bf16x8*)(Qs + r * 64 + (((4 + lgrp) ^ (r & 7)) << 3));
    f32x4 sacc[13];
    #pragma unroll
    for (int ct = 0; ct < 13; ++ct) {
      const int kr = ct * 16 + lrow;
      bf16x8 b0 = *(const bf16x8*)(Ks + kr * 64 + ((lgrp ^ (kr & 7)) << 3));
      bf16x8 b1 = *(const bf16x8*)(Ks + kr * 64 + (((4 + lgrp) ^ (kr & 7)) << 3));
      f32x4 s = {};
      s = mfma_bf16(a0, b0, s);
      s = mfma_bf16(a1, b1, s);
      sacc[ct] = s;
    }
    bf16* Pw = Ps[wave];
    float inv4[4];
    #pragma unroll
    for (int j = 0; j < 4; ++j) {
      const int prow = (lgrp << 2) + j;
      float mx = -3.0e38f;
      #pragma unroll
      for (int ct = 0; ct < 13; ++ct) {
        int c = ct * 16 + lrow;
        if (c < 197) mx = fmaxf(mx, sacc[ct][j]);
      }
      #pragma unroll
      for (int o = 1; o < 16; o <<= 1) mx = fmaxf(mx, __shfl_xor(mx, o));
      float sum = 0.0f;
      #pragma unroll
      for (int ct = 0; ct < 13; ++ct) {
        int c = ct * 16 + lrow;
        float p = (c < 197) ? __expf(sacc[ct][j] - mx) : 0.0f;
        sum += p;
        Pw[prow * 232 + c] = (bf16)p;
      }
      #pragma unroll
      for (int o = 1; o < 16; o <<= 1) sum += __shfl_xor(sum, o);
      inv4[j] = 1.0f / sum;
      Pw[prow * 232 + 208 + lrow] = (bf16)0.0f;   // zero P cols 208..223
    }
    f32x4 oacc[4] = {};
    #pragma unroll
    for (int mc = 0; mc < 7; ++mc) {              // K-dim 224
      bf16x8 pa = *(const bf16x8*)(Pw + lrow * 232 + mc * 32 + (lgrp << 3));
      #pragma unroll
      for (int n2 = 0; n2 < 4; ++n2) {
        bf16x8 vb = *(const bf16x8*)(Vs + (n2 * 16 + lrow) * 232 + mc * 32 + (lgrp << 3));
        oacc[n2] = mfma_bf16(pa, vb, oacc[n2]);
      }
    }
    #pragma unroll
    for (int n2 = 0; n2 < 4; ++n2) {
      const int d = n2 * 16 + lrow;
      #pragma unroll
      for (int j = 0; j < 4; ++j) {
        const int qrow = rt * 16 + (lgrp << 2) + j;
        if (qrow < 197)
          O[((size_t)b * 197 + qrow) * 768 + hh * 64 + d] = (bf16)(oacc[n2][j] * inv4[j]);
      }
    }
  }
}

// ---------------- driver ----------------

extern "C" void kernel_launch(void* const* d_in, const int* in_sizes, int n_in,
                              void* d_out, int out_size, void* d_ws, size_t ws_size,
                              hipStream_t stream) {
  const float* x      = (const float*)d_in[0];
  const float* w_proj = (const float*)d_in[1];
  const float* b_proj = (const float*)d_in[2];
  const float* cls    = (const float*)d_in[3];
  const float* ln1g   = (const float*)d_in[4];
  const float* ln1b   = (const float*)d_in[5];
  const float* w_qkv  = (const float*)d_in[6];
  const float* b_qkv  = (const float*)d_in[7];
  const float* w_o    = (const float*)d_in[8];
  const float* b_o    = (const float*)d_in[9];
  const float* ln2g   = (const float*)d_in[10];
  const float* ln2b   = (const float*)d_in[11];
  const float* w_fc1  = (const float*)d_in[12];
  const float* b_fc1  = (const float*)d_in[13];
  const float* w_fc2  = (const float*)d_in[14];
  const float* b_fc2  = (const float*)d_in[15];
  const float* lnfg   = (const float*)d_in[16];
  const float* lnfb   = (const float*)d_in[17];
  const float* w_h    = (const float*)d_in[18];
  const float* b_h    = (const float*)d_in[19];
  const float* w_c    = (const float*)d_in[20];
  const float* b_c    = (const float*)d_in[21];
  float* out = (float*)d_out;

  uint8_t* ws = (uint8_t*)d_ws;
  size_t off = 0;
  auto alloc = [&](size_t bytes) -> void* {
    void* p = ws + off; off += (bytes + 255) & ~(size_t)255; return p;
  };
  float* h    = (float*)alloc(6400ull * 768 * 4);   // residual fp32 (t = b*197+l)
  bf16*  ybf  = (bf16*) alloc(6400ull * 768 * 2);   // LN out bf16 (plain OR b*200+l padded)
  bf16*  ct   = (bf16*) alloc(2304ull * 6400 * 2);  // QKV^T, cols b*200+l
  bf16*  ob   = (bf16*) alloc(6400ull * 768 * 2);   // attention out bf16
  bf16*  f1   = (bf16*) alloc(6400ull * 3072 * 2);  // FC1 out bf16
  float* pos  = (float*)alloc(197ull * 768 * 4);
  bf16* wprojB = (bf16*)alloc(768ull * 768 * 2);
  bf16* wqkvB  = (bf16*)alloc(2304ull * 768 * 2);
  bf16* woB    = (bf16*)alloc(768ull * 768 * 2);
  bf16* wfc1B  = (bf16*)alloc(3072ull * 768 * 2);
  bf16* wfc2B  = (bf16*)alloc(768ull * 3072 * 2);
  bf16* whB    = (bf16*)alloc(768ull * 768 * 2);
  bf16* wcB    = (bf16*)alloc(1024ull * 768 * 2);   // rows 1000..1023 poison (finite)
  bf16* repB   = (bf16*)alloc(128ull * 768 * 2);    // rows 32..127 poison
  bf16* hidB   = (bf16*)alloc(128ull * 768 * 2);
  bf16* patches = f1;   // alias: patches dead before FC1 first writes f1

  f2b_k<<<(768 * 768 + 255) / 256, 256, 0, stream>>>(w_proj, wprojB, 768 * 768);
  f2b_k<<<(2304 * 768 + 255) / 256, 256, 0, stream>>>(w_qkv, wqkvB, 2304 * 768);
  f2b_k<<<(768 * 768 + 255) / 256, 256, 0, stream>>>(w_o, woB, 768 * 768);
  f2b_k<<<(3072 * 768 + 255) / 256, 256, 0, stream>>>(w_fc1, wfc1B, 3072 * 768);
  f2b_k<<<(768 * 3072 + 255) / 256, 256, 0, stream>>>(w_fc2, wfc2B, 768 * 3072);
  f2b_k<<<(768 * 768 + 255) / 256, 256, 0, stream>>>(w_h, whB, 768 * 768);
  f2b_k<<<(1000 * 768 + 255) / 256, 256, 0, stream>>>(w_c, wcB, 1000 * 768);
  posenc_k<<<197, 256, 0, stream>>>(pos);
  patchify_k<<<6272 * 768 / 256, 256, 0, stream>>>(x, patches);
  gemm2<64, 0><<<dim3(49, 12), 256, 0, stream>>>(patches, wprojB, 6272, 768, 768, 768, b_proj, h, nullptr);
  combine_k<<<6304 * 768 / 256, 256, 0, stream>>>(h, pos, cls);

  for (int layer = 0; layer < 12; ++layer) {
    ln4_k<1><<<1576, 256, 0, stream>>>(h, ln1g, ln1b, ybf, 6304, 768);
    // QKV^T: A = w_qkv [2304][768], B = ybf(padded rows, 6400) -> Ct [2304][6400]
    gemm2<128, 1><<<dim3(18, 50), 256, 0, stream>>>(wqkvB, ybf, 2304, 6400, 768, 6400, b_qkv, nullptr, ct);
    attn_k<<<384, 512, 0, stream>>>(ct, ob);
    gemm2<64, 2><<<dim3(50, 12), 256, 0, stream>>>(ob, woB, 6304, 768, 768, 768, b_o, h, nullptr);
    ln4_k<0><<<1576, 256, 0, stream>>>(h, ln2g, ln2b, ybf, 6304, 768);
    gemm2<128, 3><<<dim3(50, 24), 256, 0, stream>>>(ybf, wfc1B, 6304, 3072, 768, 3072, b_fc1, nullptr, f1);
    gemm2<64, 2><<<dim3(50, 12), 256, 0, stream>>>(f1, wfc2B, 6304, 768, 3072, 768, b_fc2, h, nullptr);
  }

  ln4_k<0><<<8, 256, 0, stream>>>(h, lnfg, lnfb, repB, 32, 197 * 768);
  gemm2<64, 4><<<dim3(1, 12), 256, 0, stream>>>(repB, whB, 32, 768, 768, 768, b_h, nullptr, hidB);
  gemm2<64, 5><<<dim3(1, 16), 256, 0, stream>>>(hidB, wcB, 32, 1000, 768, 1000, b_c, out, nullptr);
}

// Round 6
// 2953.571 us; speedup vs baseline: 1.1169x; 1.0029x over previous
//
#include <hip/hip_runtime.h>
#include <hip/hip_bf16.h>

// ViT forward, MI355X gfx950. Round 6: BN=128 GEMMs back to single-buffer (2-3 blocks/CU
// inter-block overlap beats intra-block dbuf at 64KiB LDS); BN=64 keeps dbuf (+226us R4/R5
// evidence); bijective XCD chunk swizzle on all GEMMs; pos-enc fused into proj epilogue.

typedef __bf16 bf16;
typedef __bf16 bf16x8 __attribute__((ext_vector_type(8)));
typedef __bf16 bf16x4 __attribute__((ext_vector_type(4)));
typedef float  f32x4  __attribute__((ext_vector_type(4)));

typedef __attribute__((address_space(1))) const unsigned int gu32;
typedef __attribute__((address_space(3))) unsigned int lu32;

static __device__ __forceinline__ f32x4 mfma_bf16(bf16x8 a, bf16x8 b, f32x4 c) {
  return __builtin_amdgcn_mfma_f32_16x16x32_bf16(a, b, c, 0, 0, 0);
}
static __device__ __forceinline__ void gll16(const bf16* g, bf16* l) {
  __builtin_amdgcn_global_load_lds((gu32*)g, (lu32*)l, 16, 0, 0);
}

// ---------------- small setup kernels ----------------

__global__ __launch_bounds__(256) void f2b_k(const float* __restrict__ a, bf16* __restrict__ o, int n) {
  int i = blockIdx.x * 256 + threadIdx.x;
  if (i < n) o[i] = (bf16)a[i];
}

__global__ __launch_bounds__(256) void posenc_k(float* __restrict__ pos) {
  int l = blockIdx.x;
  for (int d = threadIdx.x; d < 768; d += 256) {
    int ieff = d & ~1;
    float ang = (float)l * expf(-(float)ieff * (9.210340371976184f / 768.0f)); // 10000^{-i/768}
    pos[l * 768 + d] = (d & 1) ? cosf(ang) : sinf(ang);
  }
}

// patches[t, c*256+i*16+j] = x[b, c, ph*16+i, pw*16+j],  t = b*196 + ph*14 + pw
__global__ __launch_bounds__(256) void patchify_k(const float* __restrict__ x, bf16* __restrict__ p) {
  int idx = blockIdx.x * 256 + threadIdx.x;     // 6272*768 exact
  int t = idx / 768, col = idx - t * 768;
  int b = t / 196, pp = t - b * 196;
  int ph = pp / 14, pw = pp - ph * 14;
  int c = col >> 8, r = col & 255, i = r >> 4, j = r & 15;
  p[idx] = (bf16)x[((b * 3 + c) * 224 + ph * 16 + i) * 224 + pw * 16 + j];
}

// CLS row: h[b*197+0, :] = cls + pos[0]
__global__ __launch_bounds__(256) void cls_k(float* __restrict__ h, const float* __restrict__ pos,
                                             const float* __restrict__ cls) {
  int b = blockIdx.x;
  for (int d = threadIdx.x; d < 768; d += 256)
    h[((size_t)b * 197) * 768 + d] = cls[d] + pos[d];
}

// LayerNorm over 768, one wave per row, 4 rows/block, bf16 out.
// PAD=1: output row index remapped t=b*197+l -> b*200+l (QKV-GEMM B operand layout).
template<int PAD>
__global__ __launch_bounds__(256) void ln4_k(const float* __restrict__ x, const float* __restrict__ g,
                                             const float* __restrict__ bb, bf16* __restrict__ y,
                                             int nrows, int instride) {
  const int wave = threadIdx.x >> 6, lane = threadIdx.x & 63;
  const int row = blockIdx.x * 4 + wave;
  if (row >= nrows) return;
  const float4* x4 = (const float4*)(x + (size_t)row * instride);
  float4 v0 = x4[lane], v1 = x4[lane + 64], v2 = x4[lane + 128];
  float s  = v0.x + v0.y + v0.z + v0.w + v1.x + v1.y + v1.z + v1.w + v2.x + v2.y + v2.z + v2.w;
  float s2 = v0.x*v0.x + v0.y*v0.y + v0.z*v0.z + v0.w*v0.w
           + v1.x*v1.x + v1.y*v1.y + v1.z*v1.z + v1.w*v1.w
           + v2.x*v2.x + v2.y*v2.y + v2.z*v2.z + v2.w*v2.w;
  #pragma unroll
  for (int o = 1; o < 64; o <<= 1) { s += __shfl_xor(s, o); s2 += __shfl_xor(s2, o); }
  float m = s * (1.0f / 768.0f);
  float inv = rsqrtf(s2 * (1.0f / 768.0f) - m * m + 1e-5f);
  int orow = row;
  if (PAD) { int bq = row / 197; orow = row + bq * 3; }
  bf16* yr = y + (size_t)orow * 768;
  const float4* g4 = (const float4*)g;
  const float4* b4 = (const float4*)bb;
  #pragma unroll
  for (int i = 0; i < 3; ++i) {
    int idx = lane + i * 64;
    float4 vv = (i == 0) ? v0 : (i == 1) ? v1 : v2;
    float4 gv = g4[idx], bv = b4[idx];
    bf16x4 o;
    o[0] = (bf16)((vv.x - m) * inv * gv.x + bv.x);
    o[1] = (bf16)((vv.y - m) * inv * gv.y + bv.y);
    o[2] = (bf16)((vv.z - m) * inv * gv.z + bv.z);
    o[3] = (bf16)((vv.w - m) * inv * gv.w + bv.w);
    *(bf16x4*)(yr + idx * 4) = o;
  }
}

// ---------------- 128-tile NT GEMM ----------------
// C[M,N] = A[M,K] * B[N,K]^T. 128xBN tile, BK=64, 4 waves (2x2). 1D grid, bijective
// XCD chunk swizzle (x fastest within chunk -> col-panel reuse per XCD L2).
// DBUF=1: double-buffered early-issue (48 KiB @BN=64). DBUF=0: single-buffer (32 KiB @BN=128).
// EPI: 0=PROJ (h row remap + pos add, fp32)  1=QKVT (bf16, bias by ROW, rows<768 *0.125, stride ldc)
//      2=ACCUM (outF[t*768+col]+=) 3=FC1 gelu (bf16, stride 3072)
//      4=TANH (bf16, stride 768)   5=GUARDED fp32 store (stride ldc, col<N)
template<int BN, int EPI, bool DBUF>
__global__ __launch_bounds__(256) void gemm2(
    const bf16* __restrict__ A, const bf16* __restrict__ B,
    int M, int N, int K, int ldc, int gx, const float* __restrict__ bias,
    const float* __restrict__ posw,
    float* __restrict__ outF, bf16* __restrict__ outB)
{
  constexpr int WN = (BN == 128) ? 64 : 32;
  constexpr int NI = WN / 16;
  constexpr int NB = BN / 32;
  constexpr int NBUF = DBUF ? 2 : 1;
  __shared__ alignas(16) bf16 As[NBUF][128 * 64];
  __shared__ alignas(16) bf16 Bs[NBUF][BN * 64];
  const int tid = threadIdx.x;
  const int lane = tid & 63, wave = tid >> 6;
  const int wr = wave >> 1, wc = wave & 1;
  const int lrow = lane & 15, lgrp = lane >> 4;

  // bijective XCD chunk swizzle (m204)
  const int nwg = gridDim.x, bid0 = blockIdx.x;
  const int xcd = bid0 & 7, loc = bid0 >> 3;
  const int q = nwg >> 3, r = nwg & 7;
  const int nb = (xcd < r ? xcd * (q + 1) : r * (q + 1) + (xcd - r) * q) + loc;
  const int bx = nb % gx, by = nb / gx;
  const int row0 = bx * 128, col0 = by * BN;

  f32x4 acc[4][NI] = {};
  const bf16* Agb = A + (size_t)row0 * K;
  const bf16* Bgb = B + (size_t)col0 * K;
  const int srow = lane >> 3, schunk = lane & 7;
  const int nk = K >> 6;

  auto stageA = [&](const bf16* Ag, bf16* Ad) {
    #pragma unroll
    for (int i = 0; i < 4; ++i) {
      int rr = (wave * 4 + i) * 8 + srow;
      int g = schunk ^ (rr & 7);
      gll16(Ag + (size_t)rr * K + g * 8, Ad + (wave * 4 + i) * 512);
    }
  };
  auto stageB = [&](const bf16* Bg, bf16* Bd) {
    #pragma unroll
    for (int i = 0; i < NB; ++i) {
      int rr = (wave * NB + i) * 8 + srow;
      int g = schunk ^ (rr & 7);
      gll16(Bg + (size_t)rr * K + g * 8, Bd + (wave * NB + i) * 512);
    }
  };
  auto compute = [&](const bf16* Ac, const bf16* Bc) {
    #pragma unroll
    for (int kk = 0; kk < 2; ++kk) {
      bf16x8 af[4], bfr[NI];
      #pragma unroll
      for (int mi = 0; mi < 4; ++mi) {
        int rrr = wr * 64 + mi * 16 + lrow;
        af[mi] = *(const bf16x8*)(Ac + rrr * 64 + (((kk * 4 + lgrp) ^ (rrr & 7)) << 3));
      }
      #pragma unroll
      for (int ni = 0; ni < NI; ++ni) {
        int rrr = wc * WN + ni * 16 + lrow;
        bfr[ni] = *(const bf16x8*)(Bc + rrr * 64 + (((kk * 4 + lgrp) ^ (rrr & 7)) << 3));
      }
      __builtin_amdgcn_s_setprio(1);
      #pragma unroll
      for (int mi = 0; mi < 4; ++mi)
        #pragma unroll
        for (int ni = 0; ni < NI; ++ni)
          acc[mi][ni] = mfma_bf16(af[mi], bfr[ni], acc[mi][ni]);
      __builtin_amdgcn_s_setprio(0);
    }
  };

  if constexpr (DBUF) {
    stageA(Agb, As[0]); stageB(Bgb, Bs[0]);
    __syncthreads();
    int cur = 0;
    for (int kt = 0; kt < nk; ++kt) {
      if (kt + 1 < nk) {
        stageA(Agb + (kt + 1) * 64, As[cur ^ 1]);
        stageB(Bgb + (kt + 1) * 64, Bs[cur ^ 1]);
      }
      compute(As[cur], Bs[cur]);
      __syncthreads();
      cur ^= 1;
    }
  } else {
    for (int kt = 0; kt < nk; ++kt) {
      stageA(Agb + kt * 64, As[0]); stageB(Bgb + kt * 64, Bs[0]);
      __syncthreads();
      compute(As[0], Bs[0]);
      __syncthreads();
    }
  }

  // epilogue: C frag layout col = lane&15, row = (lane>>4)*4 + j
  #pragma unroll
  for (int ni = 0; ni < NI; ++ni) {
    const int col = col0 + wc * WN + ni * 16 + lrow;
    float bs = 0.0f;
    if (EPI != 1) {
      if (EPI == 5) bs = (col < N) ? bias[col] : 0.0f;
      else          bs = bias[col];
    }
    #pragma unroll
    for (int mi = 0; mi < 4; ++mi) {
      const int rbase = row0 + wr * 64 + mi * 16 + (lgrp << 2);
      #pragma unroll
      for (int j = 0; j < 4; ++j) {
        const int t = rbase + j;
        if (EPI == 1) {
          float val = acc[mi][ni][j] + bias[t];
          if (t < 768) val *= 0.125f;
          outB[(size_t)t * ldc + col] = (bf16)val;
        } else {
          if (t >= M) continue;
          float val = acc[mi][ni][j] + bs;
          if (EPI == 0) {
            int b = t / 196, p = t - b * 196;
            outF[((size_t)(b * 197 + 1 + p)) * 768 + col] = val + posw[(size_t)(1 + p) * 768 + col];
          } else if (EPI == 2) {
            outF[(size_t)t * 768 + col] += val;
          } else if (EPI == 3) {
            outB[(size_t)t * 3072 + col] = (bf16)(0.5f * val * (1.0f + erff(val * 0.70710678118654752f)));
          } else if (EPI == 4) {
            outB[(size_t)t * 768 + col] = (bf16)tanhf(val);
          } else {
            if (col < N) outF[(size_t)t * ldc + col] = val;
          }
        }
      }
    }
  }
}

// ---------------- attention: one block per (b, head), 8 waves ----------------
// Ct: QKV^T [2304][6400] bf16, cols = b*200 + l (rows n = comp*768 + d*12 + h; Q pre-scaled 1/8).
// O: [6304][768] bf16 (t = b*197 + l).
__global__ __launch_bounds__(512) void attn_k(const bf16* __restrict__ Ct, bf16* __restrict__ O) {
  __shared__ alignas(16) bf16 Ks[208 * 64];       // [l][d] XOR-swizzled
  __shared__ alignas(16) bf16 Qs[208 * 64];       // [l][d] XOR-swizzled
  __shared__ alignas(16) bf16 Vs[64 * 232];       // [d][l] pad 232, cols 197..231 zeroed
  __shared__ alignas(16) bf16 Ps[8][16 * 232];    // per-wave P tile
  const int bh = blockIdx.x;
  const int b = bh / 12, hh = bh - b * 12;
  const int tid = threadIdx.x, lane = tid & 63, wave = tid >> 6;
  const int lrow = lane & 15, lgrp = lane >> 4;
  const size_t tc0 = (size_t)b * 200;

  for (int task = tid; task < 1600; task += 512) {
    int d = task / 25, lc = task - d * 25;
    int l0 = lc * 8;
    const size_t cb = tc0 + l0;
    bf16x8 qv = *(const bf16x8*)(Ct + ((size_t)(d * 12 + hh)) * 6400 + cb);
    bf16x8 kv = *(const bf16x8*)(Ct + ((size_t)(768 + d * 12 + hh)) * 6400 + cb);
    bf16x8 vv = *(const bf16x8*)(Ct + ((size_t)(1536 + d * 12 + hh)) * 6400 + cb);
    #pragma unroll
    for (int e = 0; e < 8; ++e) {
      int l = l0 + e;
      int sw = ((((d >> 3) ^ (l & 7)) << 3) | (d & 7));
      Ks[l * 64 + sw] = kv[e];
      Qs[l * 64 + sw] = qv[e];
    }
    *(bf16x8*)(Vs + d * 232 + l0) = vv;
  }
  for (int q = tid; q < 64 * 35; q += 512) {      // zero V cols 197..231
    int d = q / 35, c = 197 + (q - d * 35);
    Vs[d * 232 + c] = (bf16)0.0f;
  }
  __syncthreads();

  for (int rt = wave; rt < 13; rt += 8) {
    const int r = rt * 16 + lrow;
    bf16x8 a0 = *(const bf16x8*)(Qs + r * 64 + ((lgrp ^ (r & 7)) << 3));
    bf16x8 a1 = *(const bf16x8*)(Qs + r * 64 + (((4 + lgrp) ^ (r & 7)) << 3));
    f32x4 sacc[13];
    #pragma unroll
    for (int ct = 0; ct < 13; ++ct) {
      const int kr = ct * 16 + lrow;
      bf16x8 b0 = *(const bf16x8*)(Ks + kr * 64 + ((lgrp ^ (kr & 7)) << 3));
      bf16x8 b1 = *(const bf16x8*)(Ks + kr * 64 + (((4 + lgrp) ^ (kr & 7)) << 3));
      f32x4 s = {};
      s = mfma_bf16(a0, b0, s);
      s = mfma_bf16(a1, b1, s);
      sacc[ct] = s;
    }
    bf16* Pw = Ps[wave];
    float inv4[4];
    #pragma unroll
    for (int j = 0; j < 4; ++j) {
      const int prow = (lgrp << 2) + j;
      float mx = -3.0e38f;
      #pragma unroll
      for (int ct = 0; ct < 13; ++ct) {
        int c = ct * 16 + lrow;
        if (c < 197) mx = fmaxf(mx, sacc[ct][j]);
      }
      #pragma unroll
      for (int o = 1; o < 16; o <<= 1) mx = fmaxf(mx, __shfl_xor(mx, o));
      float sum = 0.0f;
      #pragma unroll
      for (int ct = 0; ct < 13; ++ct) {
        int c = ct * 16 + lrow;
        float p = (c < 197) ? __expf(sacc[ct][j] - mx) : 0.0f;
        sum += p;
        Pw[prow * 232 + c] = (bf16)p;
      }
      #pragma unroll
      for (int o = 1; o < 16; o <<= 1) sum += __shfl_xor(sum, o);
      inv4[j] = 1.0f / sum;
      Pw[prow * 232 + 208 + lrow] = (bf16)0.0f;   // zero P cols 208..223
    }
    f32x4 oacc[4] = {};
    #pragma unroll
    for (int mc = 0; mc < 7; ++mc) {              // K-dim 224
      bf16x8 pa = *(const bf16x8*)(Pw + lrow * 232 + mc * 32 + (lgrp << 3));
      #pragma unroll
      for (int n2 = 0; n2 < 4; ++n2) {
        bf16x8 vb = *(const bf16x8*)(Vs + (n2 * 16 + lrow) * 232 + mc * 32 + (lgrp << 3));
        oacc[n2] = mfma_bf16(pa, vb, oacc[n2]);
      }
    }
    #pragma unroll
    for (int n2 = 0; n2 < 4; ++n2) {
      const int d = n2 * 16 + lrow;
      #pragma unroll
      for (int j = 0; j < 4; ++j) {
        const int qrow = rt * 16 + (lgrp << 2) + j;
        if (qrow < 197)
          O[((size_t)b * 197 + qrow) * 768 + hh * 64 + d] = (bf16)(oacc[n2][j] * inv4[j]);
      }
    }
  }
}

// ---------------- driver ----------------

extern "C" void kernel_launch(void* const* d_in, const int* in_sizes, int n_in,
                              void* d_out, int out_size, void* d_ws, size_t ws_size,
                              hipStream_t stream) {
  const float* x      = (const float*)d_in[0];
  const float* w_proj = (const float*)d_in[1];
  const float* b_proj = (const float*)d_in[2];
  const float* cls    = (const float*)d_in[3];
  const float* ln1g   = (const float*)d_in[4];
  const float* ln1b   = (const float*)d_in[5];
  const float* w_qkv  = (const float*)d_in[6];
  const float* b_qkv  = (const float*)d_in[7];
  const float* w_o    = (const float*)d_in[8];
  const float* b_o    = (const float*)d_in[9];
  const float* ln2g   = (const float*)d_in[10];
  const float* ln2b   = (const float*)d_in[11];
  const float* w_fc1  = (const float*)d_in[12];
  const float* b_fc1  = (const float*)d_in[13];
  const float* w_fc2  = (const float*)d_in[14];
  const float* b_fc2  = (const float*)d_in[15];
  const float* lnfg   = (const float*)d_in[16];
  const float* lnfb   = (const float*)d_in[17];
  const float* w_h    = (const float*)d_in[18];
  const float* b_h    = (const float*)d_in[19];
  const float* w_c    = (const float*)d_in[20];
  const float* b_c    = (const float*)d_in[21];
  float* out = (float*)d_out;

  uint8_t* ws = (uint8_t*)d_ws;
  size_t off = 0;
  auto alloc = [&](size_t bytes) -> void* {
    void* p = ws + off; off += (bytes + 255) & ~(size_t)255; return p;
  };
  float* h    = (float*)alloc(6400ull * 768 * 4);   // residual fp32 (t = b*197+l)
  bf16*  ybf  = (bf16*) alloc(6400ull * 768 * 2);   // LN out bf16 (plain OR b*200+l padded)
  bf16*  ct   = (bf16*) alloc(2304ull * 6400 * 2);  // QKV^T, cols b*200+l
  bf16*  ob   = (bf16*) alloc(6400ull * 768 * 2);   // attention out bf16
  bf16*  f1   = (bf16*) alloc(6400ull * 3072 * 2);  // FC1 out bf16
  float* pos  = (float*)alloc(197ull * 768 * 4);
  bf16* wprojB = (bf16*)alloc(768ull * 768 * 2);
  bf16* wqkvB  = (bf16*)alloc(2304ull * 768 * 2);
  bf16* woB    = (bf16*)alloc(768ull * 768 * 2);
  bf16* wfc1B  = (bf16*)alloc(3072ull * 768 * 2);
  bf16* wfc2B  = (bf16*)alloc(768ull * 3072 * 2);
  bf16* whB    = (bf16*)alloc(768ull * 768 * 2);
  bf16* wcB    = (bf16*)alloc(1024ull * 768 * 2);   // rows 1000..1023 poison (finite)
  bf16* repB   = (bf16*)alloc(128ull * 768 * 2);    // rows 32..127 poison
  bf16* hidB   = (bf16*)alloc(128ull * 768 * 2);
  bf16* patches = f1;   // alias: patches dead before FC1 first writes f1

  f2b_k<<<(768 * 768 + 255) / 256, 256, 0, stream>>>(w_proj, wprojB, 768 * 768);
  f2b_k<<<(2304 * 768 + 255) / 256, 256, 0, stream>>>(w_qkv, wqkvB, 2304 * 768);
  f2b_k<<<(768 * 768 + 255) / 256, 256, 0, stream>>>(w_o, woB, 768 * 768);
  f2b_k<<<(3072 * 768 + 255) / 256, 256, 0, stream>>>(w_fc1, wfc1B, 3072 * 768);
  f2b_k<<<(768 * 3072 + 255) / 256, 256, 0, stream>>>(w_fc2, wfc2B, 768 * 3072);
  f2b_k<<<(768 * 768 + 255) / 256, 256, 0, stream>>>(w_h, whB, 768 * 768);
  f2b_k<<<(1000 * 768 + 255) / 256, 256, 0, stream>>>(w_c, wcB, 1000 * 768);
  posenc_k<<<197, 256, 0, stream>>>(pos);
  patchify_k<<<6272 * 768 / 256, 256, 0, stream>>>(x, patches);
  gemm2<64, 0, true><<<49 * 12, 256, 0, stream>>>(patches, wprojB, 6272, 768, 768, 768, 49,
                                                  b_proj, pos, h, nullptr);
  cls_k<<<32, 256, 0, stream>>>(h, pos, cls);

  for (int layer = 0; layer < 12; ++layer) {
    ln4_k<1><<<1576, 256, 0, stream>>>(h, ln1g, ln1b, ybf, 6304, 768);
    // QKV^T: A = w_qkv [2304][768], B = ybf(padded rows, 6400) -> Ct [2304][6400]
    gemm2<128, 1, false><<<18 * 50, 256, 0, stream>>>(wqkvB, ybf, 2304, 6400, 768, 6400, 18,
                                                      b_qkv, nullptr, nullptr, ct);
    attn_k<<<384, 512, 0, stream>>>(ct, ob);
    gemm2<64, 2, true><<<50 * 12, 256, 0, stream>>>(ob, woB, 6304, 768, 768, 768, 50,
                                                    b_o, nullptr, h, nullptr);
    ln4_k<0><<<1576, 256, 0, stream>>>(h, ln2g, ln2b, ybf, 6304, 768);
    gemm2<128, 3, false><<<50 * 24, 256, 0, stream>>>(ybf, wfc1B, 6304, 3072, 768, 3072, 50,
                                                      b_fc1, nullptr, nullptr, f1);
    gemm2<64, 2, true><<<50 * 12, 256, 0, stream>>>(f1, wfc2B, 6304, 768, 3072, 768, 50,
                                                    b_fc2, nullptr, h, nullptr);
  }

  ln4_k<0><<<8, 256, 0, stream>>>(h, lnfg, lnfb, repB, 32, 197 * 768);
  gemm2<64, 4, true><<<1 * 12, 256, 0, stream>>>(repB, whB, 32, 768, 768, 768, 1,
                                                 b_h, nullptr, nullptr, hidB);
  gemm2<64, 5, true><<<1 * 16, 256, 0, stream>>>(hidB, wcB, 32, 1000, 768, 1000, 1,
                                                 b_c, nullptr, out, nullptr);
}

// Round 7
// 2934.677 us; speedup vs baseline: 1.1241x; 1.0064x over previous
//
#include <hip/hip_runtime.h>
#include <hip/hip_bf16.h>

// ViT forward, MI355X gfx950. Round 7: 128x256-tile GEMM with per-wave 64x128 accumulator
// for QKV/FC1 (fixes LDS-read-bound regime: 375B/MFMA vs 500B/MFMA), per-GEMM XCD
// chunk-order (keep small matrix L2-resident), strength-reduced staging addresses.

typedef __bf16 bf16;
typedef __bf16 bf16x8 __attribute__((ext_vector_type(8)));
typedef __bf16 bf16x4 __attribute__((ext_vector_type(4)));
typedef float  f32x4  __attribute__((ext_vector_type(4)));

typedef __attribute__((address_space(1))) const unsigned int gu32;
typedef __attribute__((address_space(3))) unsigned int lu32;

static __device__ __forceinline__ f32x4 mfma_bf16(bf16x8 a, bf16x8 b, f32x4 c) {
  return __builtin_amdgcn_mfma_f32_16x16x32_bf16(a, b, c, 0, 0, 0);
}
static __device__ __forceinline__ void gll16(const bf16* g, bf16* l) {
  __builtin_amdgcn_global_load_lds((gu32*)g, (lu32*)l, 16, 0, 0);
}

// ---------------- small setup kernels ----------------

__global__ __launch_bounds__(256) void f2b_k(const float* __restrict__ a, bf16* __restrict__ o, int n) {
  int i = blockIdx.x * 256 + threadIdx.x;
  if (i < n) o[i] = (bf16)a[i];
}

__global__ __launch_bounds__(256) void posenc_k(float* __restrict__ pos) {
  int l = blockIdx.x;
  for (int d = threadIdx.x; d < 768; d += 256) {
    int ieff = d & ~1;
    float ang = (float)l * expf(-(float)ieff * (9.210340371976184f / 768.0f)); // 10000^{-i/768}
    pos[l * 768 + d] = (d & 1) ? cosf(ang) : sinf(ang);
  }
}

// patches[t, c*256+i*16+j] = x[b, c, ph*16+i, pw*16+j],  t = b*196 + ph*14 + pw
__global__ __launch_bounds__(256) void patchify_k(const float* __restrict__ x, bf16* __restrict__ p) {
  int idx = blockIdx.x * 256 + threadIdx.x;     // 6272*768 exact
  int t = idx / 768, col = idx - t * 768;
  int b = t / 196, pp = t - b * 196;
  int ph = pp / 14, pw = pp - ph * 14;
  int c = col >> 8, r = col & 255, i = r >> 4, j = r & 15;
  p[idx] = (bf16)x[((b * 3 + c) * 224 + ph * 16 + i) * 224 + pw * 16 + j];
}

// CLS row: h[b*197+0, :] = cls + pos[0]
__global__ __launch_bounds__(256) void cls_k(float* __restrict__ h, const float* __restrict__ pos,
                                             const float* __restrict__ cls) {
  int b = blockIdx.x;
  for (int d = threadIdx.x; d < 768; d += 256)
    h[((size_t)b * 197) * 768 + d] = cls[d] + pos[d];
}

// LayerNorm over 768, one wave per row, 4 rows/block, bf16 out.
// PAD=1: output row index remapped t=b*197+l -> b*200+l (QKV-GEMM B operand layout).
template<int PAD>
__global__ __launch_bounds__(256) void ln4_k(const float* __restrict__ x, const float* __restrict__ g,
                                             const float* __restrict__ bb, bf16* __restrict__ y,
                                             int nrows, int instride) {
  const int wave = threadIdx.x >> 6, lane = threadIdx.x & 63;
  const int row = blockIdx.x * 4 + wave;
  if (row >= nrows) return;
  const float4* x4 = (const float4*)(x + (size_t)row * instride);
  float4 v0 = x4[lane], v1 = x4[lane + 64], v2 = x4[lane + 128];
  float s  = v0.x + v0.y + v0.z + v0.w + v1.x + v1.y + v1.z + v1.w + v2.x + v2.y + v2.z + v2.w;
  float s2 = v0.x*v0.x + v0.y*v0.y + v0.z*v0.z + v0.w*v0.w
           + v1.x*v1.x + v1.y*v1.y + v1.z*v1.z + v1.w*v1.w
           + v2.x*v2.x + v2.y*v2.y + v2.z*v2.z + v2.w*v2.w;
  #pragma unroll
  for (int o = 1; o < 64; o <<= 1) { s += __shfl_xor(s, o); s2 += __shfl_xor(s2, o); }
  float m = s * (1.0f / 768.0f);
  float inv = rsqrtf(s2 * (1.0f / 768.0f) - m * m + 1e-5f);
  int orow = row;
  if (PAD) { int bq = row / 197; orow = row + bq * 3; }
  bf16* yr = y + (size_t)orow * 768;
  const float4* g4 = (const float4*)g;
  const float4* b4 = (const float4*)bb;
  #pragma unroll
  for (int i = 0; i < 3; ++i) {
    int idx = lane + i * 64;
    float4 vv = (i == 0) ? v0 : (i == 1) ? v1 : v2;
    float4 gv = g4[idx], bv = b4[idx];
    bf16x4 o;
    o[0] = (bf16)((vv.x - m) * inv * gv.x + bv.x);
    o[1] = (bf16)((vv.y - m) * inv * gv.y + bv.y);
    o[2] = (bf16)((vv.z - m) * inv * gv.z + bv.z);
    o[3] = (bf16)((vv.w - m) * inv * gv.w + bv.w);
    *(bf16x4*)(yr + idx * 4) = o;
  }
}

// ---------------- NT GEMM ----------------
// C[M,N] = A[M,K] * B[N,K]^T. 128xBN tile, BK=64, 4 waves.
// BN=64: per-wave 64x32 (2x2 wave grid), optional dbuf (48 KiB).
// BN=256: per-wave 64x128 (2x2 wave grid), single-buffer (48 KiB), ni in 4-chunks.
// 1D grid + bijective XCD chunk swizzle; xfast picks chunk-internal order so the
// LARGE matrix is read once per chunk and the small one stays L2-resident.
// EPI: 0=PROJ (h row remap + pos add, fp32)  1=QKVT (bf16, bias by ROW, rows<768 *0.125)
//      2=ACCUM (outF[t*768+col]+=) 3=FC1 gelu (bf16, stride 3072)
//      4=TANH (bf16, stride 768)   5=GUARDED fp32 store (stride ldc, col<N)
template<int BN, int EPI, bool DBUF>
__global__ __launch_bounds__(256, 2) void gemm2(
    const bf16* __restrict__ A, const bf16* __restrict__ B,
    int M, int N, int K, int ldc, int gx, int xfast, const float* __restrict__ bias,
    const float* __restrict__ posw,
    float* __restrict__ outF, bf16* __restrict__ outB)
{
  constexpr int WN = (BN == 256) ? 128 : 32;
  constexpr int NI = WN / 16;
  constexpr int NC = (NI > 4) ? 4 : NI;       // ni chunk (bounds live bfr regs)
  constexpr int NB = BN / 32;                 // B stage shots per wave
  constexpr int NBUF = DBUF ? 2 : 1;
  __shared__ alignas(16) bf16 As[NBUF][128 * 64];
  __shared__ alignas(16) bf16 Bs[NBUF][BN * 64];
  const int tid = threadIdx.x;
  const int lane = tid & 63, wave = tid >> 6;
  const int wr = wave >> 1, wc = wave & 1;
  const int lrow = lane & 15, lgrp = lane >> 4;

  // bijective XCD chunk swizzle (m204) + per-call chunk-internal order
  const int nwg = gridDim.x, bid0 = blockIdx.x;
  const int xcd = bid0 & 7, loc = bid0 >> 3;
  const int q = nwg >> 3, r = nwg & 7;
  const int nb = (xcd < r ? xcd * (q + 1) : r * (q + 1) + (xcd - r) * q) + loc;
  int bx, by;
  if (xfast) { bx = nb % gx; by = nb / gx; }
  else       { int gy = nwg / gx; by = nb % gy; bx = nb / gy; }
  const int row0 = bx * 128, col0 = by * BN;

  f32x4 acc[4][NI] = {};
  const int srow = lane >> 3, schunk = lane & 7;
  const int nk = K >> 6;

  // strength-reduced staging pointers (advance by 64 elements per K-step)
  const bf16* aptr[4];
  const bf16* bptr[NB];
  {
    const bf16* Agb = A + (size_t)row0 * K;
    const bf16* Bgb = B + (size_t)col0 * K;
    #pragma unroll
    for (int i = 0; i < 4; ++i) {
      int rr = (wave * 4 + i) * 8 + srow;
      aptr[i] = Agb + (size_t)rr * K + ((schunk ^ (rr & 7)) << 3);
    }
    #pragma unroll
    for (int i = 0; i < NB; ++i) {
      int rr = (wave * NB + i) * 8 + srow;
      bptr[i] = Bgb + (size_t)rr * K + ((schunk ^ (rr & 7)) << 3);
    }
  }
  // precomputed LDS element offsets (loop-invariant)
  int aoff[2][4], boff[2][NI];
  #pragma unroll
  for (int kk = 0; kk < 2; ++kk) {
    #pragma unroll
    for (int mi = 0; mi < 4; ++mi) {
      int rr = wr * 64 + mi * 16 + lrow;
      aoff[kk][mi] = rr * 64 + (((kk * 4 + lgrp) ^ (rr & 7)) << 3);
    }
    #pragma unroll
    for (int ni = 0; ni < NI; ++ni) {
      int rr = wc * WN + ni * 16 + lrow;
      boff[kk][ni] = rr * 64 + (((kk * 4 + lgrp) ^ (rr & 7)) << 3);
    }
  }

  auto stage = [&](int buf) {
    #pragma unroll
    for (int i = 0; i < 4; ++i) {
      gll16(aptr[i], As[buf] + (wave * 4 + i) * 512);
      aptr[i] += 64;
    }
    #pragma unroll
    for (int i = 0; i < NB; ++i) {
      gll16(bptr[i], Bs[buf] + (wave * NB + i) * 512);
      bptr[i] += 64;
    }
  };
  auto compute = [&](const bf16* Ac, const bf16* Bc) {
    #pragma unroll
    for (int kk = 0; kk < 2; ++kk) {
      bf16x8 af[4];
      #pragma unroll
      for (int mi = 0; mi < 4; ++mi) af[mi] = *(const bf16x8*)(Ac + aoff[kk][mi]);
      #pragma unroll
      for (int nh = 0; nh < NI / NC; ++nh) {
        bf16x8 bfr[NC];
        #pragma unroll
        for (int nj = 0; nj < NC; ++nj)
          bfr[nj] = *(const bf16x8*)(Bc + boff[kk][nh * NC + nj]);
        __builtin_amdgcn_s_setprio(1);
        #pragma unroll
        for (int mi = 0; mi < 4; ++mi)
          #pragma unroll
          for (int nj = 0; nj < NC; ++nj)
            acc[mi][nh * NC + nj] = mfma_bf16(af[mi], bfr[nj], acc[mi][nh * NC + nj]);
        __builtin_amdgcn_s_setprio(0);
      }
    }
  };

  if constexpr (DBUF) {
    stage(0);
    __syncthreads();
    int cur = 0;
    for (int kt = 0; kt < nk; ++kt) {
      if (kt + 1 < nk) stage(cur ^ 1);
      compute(As[cur], Bs[cur]);
      __syncthreads();
      cur ^= 1;
    }
  } else {
    for (int kt = 0; kt < nk; ++kt) {
      stage(0);
      __syncthreads();
      compute(As[0], Bs[0]);
      __syncthreads();
    }
  }

  // epilogue: C frag layout col = lane&15, row = (lane>>4)*4 + j
  #pragma unroll
  for (int ni = 0; ni < NI; ++ni) {
    const int col = col0 + wc * WN + ni * 16 + lrow;
    float bs = 0.0f;
    if (EPI != 1) {
      if (EPI == 5) bs = (col < N) ? bias[col] : 0.0f;
      else          bs = bias[col];
    }
    #pragma unroll
    for (int mi = 0; mi < 4; ++mi) {
      const int rbase = row0 + wr * 64 + mi * 16 + (lgrp << 2);
      #pragma unroll
      for (int j = 0; j < 4; ++j) {
        const int t = rbase + j;
        if (EPI == 1) {
          float val = acc[mi][ni][j] + bias[t];
          if (t < 768) val *= 0.125f;
          outB[(size_t)t * ldc + col] = (bf16)val;
        } else {
          if (t >= M) continue;
          float val = acc[mi][ni][j] + bs;
          if (EPI == 0) {
            int b = t / 196, p = t - b * 196;
            outF[((size_t)(b * 197 + 1 + p)) * 768 + col] = val + posw[(size_t)(1 + p) * 768 + col];
          } else if (EPI == 2) {
            outF[(size_t)t * 768 + col] += val;
          } else if (EPI == 3) {
            outB[(size_t)t * 3072 + col] = (bf16)(0.5f * val * (1.0f + erff(val * 0.70710678118654752f)));
          } else if (EPI == 4) {
            outB[(size_t)t * 768 + col] = (bf16)tanhf(val);
          } else {
            if (col < N) outF[(size_t)t * ldc + col] = val;
          }
        }
      }
    }
  }
}

// ---------------- attention: one block per (b, head), 8 waves ----------------
// Ct: QKV^T [2304][6400] bf16, cols = b*200 + l (rows n = comp*768 + d*12 + h; Q pre-scaled 1/8).
// O: [6304][768] bf16 (t = b*197 + l).
__global__ __launch_bounds__(512) void attn_k(const bf16* __restrict__ Ct, bf16* __restrict__ O) {
  __shared__ alignas(16) bf16 Ks[208 * 64];       // [l][d] XOR-swizzled
  __shared__ alignas(16) bf16 Qs[208 * 64];       // [l][d] XOR-swizzled
  __shared__ alignas(16) bf16 Vs[64 * 232];       // [d][l] pad 232, cols 197..231 zeroed
  __shared__ alignas(16) bf16 Ps[8][16 * 232];    // per-wave P tile
  const int bh = blockIdx.x;
  const int b = bh / 12, hh = bh - b * 12;
  const int tid = threadIdx.x, lane = tid & 63, wave = tid >> 6;
  const int lrow = lane & 15, lgrp = lane >> 4;
  const size_t tc0 = (size_t)b * 200;

  for (int task = tid; task < 1600; task += 512) {
    int d = task / 25, lc = task - d * 25;
    int l0 = lc * 8;
    const size_t cb = tc0 + l0;
    bf16x8 qv = *(const bf16x8*)(Ct + ((size_t)(d * 12 + hh)) * 6400 + cb);
    bf16x8 kv = *(const bf16x8*)(Ct + ((size_t)(768 + d * 12 + hh)) * 6400 + cb);
    bf16x8 vv = *(const bf16x8*)(Ct + ((size_t)(1536 + d * 12 + hh)) * 6400 + cb);
    #pragma unroll
    for (int e = 0; e < 8; ++e) {
      int l = l0 + e;
      int sw = ((((d >> 3) ^ (l & 7)) << 3) | (d & 7));
      Ks[l * 64 + sw] = kv[e];
      Qs[l * 64 + sw] = qv[e];
    }
    *(bf16x8*)(Vs + d * 232 + l0) = vv;
  }
  for (int q = tid; q < 64 * 35; q += 512) {      // zero V cols 197..231
    int d = q / 35, c = 197 + (q - d * 35);
    Vs[d * 232 + c] = (bf16)0.0f;
  }
  __syncthreads();

  for (int rt = wave; rt < 13; rt += 8) {
    const int r = rt * 16 + lrow;
    bf16x8 a0 = *(const bf16x8*)(Qs + r * 64 + ((lgrp ^ (r & 7)) << 3));
    bf16x8 a1 = *(const bf16x8*)(Qs + r * 64 + (((4 + lgrp) ^ (r & 7)) << 3));
    f32x4 sacc[13];
    #pragma unroll
    for (int ct = 0; ct < 13; ++ct) {
      const int kr = ct * 16 + lrow;
      bf16x8 b0 = *(const bf16x8*)(Ks + kr * 64 + ((lgrp ^ (kr & 7)) << 3));
      bf16x8 b1 = *(const bf16x8*)(Ks + kr * 64 + (((4 + lgrp) ^ (kr & 7)) << 3));
      f32x4 s = {};
      s = mfma_bf16(a0, b0, s);
      s = mfma_bf16(a1, b1, s);
      sacc[ct] = s;
    }
    bf16* Pw = Ps[wave];
    float inv4[4];
    #pragma unroll
    for (int j = 0; j < 4; ++j) {
      const int prow = (lgrp << 2) + j;
      float mx = -3.0e38f;
      #pragma unroll
      for (int ct = 0; ct < 13; ++ct) {
        int c = ct * 16 + lrow;
        if (c < 197) mx = fmaxf(mx, sacc[ct][j]);
      }
      #pragma unroll
      for (int o = 1; o < 16; o <<= 1) mx = fmaxf(mx, __shfl_xor(mx, o));
      float sum = 0.0f;
      #pragma unroll
      for (int ct = 0; ct < 13; ++ct) {
        int c = ct * 16 + lrow;
        float p = (c < 197) ? __expf(sacc[ct][j] - mx) : 0.0f;
        sum += p;
        Pw[prow * 232 + c] = (bf16)p;
      }
      #pragma unroll
      for (int o = 1; o < 16; o <<= 1) sum += __shfl_xor(sum, o);
      inv4[j] = 1.0f / sum;
      Pw[prow * 232 + 208 + lrow] = (bf16)0.0f;   // zero P cols 208..223
    }
    f32x4 oacc[4] = {};
    #pragma unroll
    for (int mc = 0; mc < 7; ++mc) {              // K-dim 224
      bf16x8 pa = *(const bf16x8*)(Pw + lrow * 232 + mc * 32 + (lgrp << 3));
      #pragma unroll
      for (int n2 = 0; n2 < 4; ++n2) {
        bf16x8 vb = *(const bf16x8*)(Vs + (n2 * 16 + lrow) * 232 + mc * 32 + (lgrp << 3));
        oacc[n2] = mfma_bf16(pa, vb, oacc[n2]);
      }
    }
    #pragma unroll
    for (int n2 = 0; n2 < 4; ++n2) {
      const int d = n2 * 16 + lrow;
      #pragma unroll
      for (int j = 0; j < 4; ++j) {
        const int qrow = rt * 16 + (lgrp << 2) + j;
        if (qrow < 197)
          O[((size_t)b * 197 + qrow) * 768 + hh * 64 + d] = (bf16)(oacc[n2][j] * inv4[j]);
      }
    }
  }
}

// ---------------- driver ----------------

extern "C" void kernel_launch(void* const* d_in, const int* in_sizes, int n_in,
                              void* d_out, int out_size, void* d_ws, size_t ws_size,
                              hipStream_t stream) {
  const float* x      = (const float*)d_in[0];
  const float* w_proj = (const float*)d_in[1];
  const float* b_proj = (const float*)d_in[2];
  const float* cls    = (const float*)d_in[3];
  const float* ln1g   = (const float*)d_in[4];
  const float* ln1b   = (const float*)d_in[5];
  const float* w_qkv  = (const float*)d_in[6];
  const float* b_qkv  = (const float*)d_in[7];
  const float* w_o    = (const float*)d_in[8];
  const float* b_o    = (const float*)d_in[9];
  const float* ln2g   = (const float*)d_in[10];
  const float* ln2b   = (const float*)d_in[11];
  const float* w_fc1  = (const float*)d_in[12];
  const float* b_fc1  = (const float*)d_in[13];
  const float* w_fc2  = (const float*)d_in[14];
  const float* b_fc2  = (const float*)d_in[15];
  const float* lnfg   = (const float*)d_in[16];
  const float* lnfb   = (const float*)d_in[17];
  const float* w_h    = (const float*)d_in[18];
  const float* b_h    = (const float*)d_in[19];
  const float* w_c    = (const float*)d_in[20];
  const float* b_c    = (const float*)d_in[21];
  float* out = (float*)d_out;

  uint8_t* ws = (uint8_t*)d_ws;
  size_t off = 0;
  auto alloc = [&](size_t bytes) -> void* {
    void* p = ws + off; off += (bytes + 255) & ~(size_t)255; return p;
  };
  float* h    = (float*)alloc(6400ull * 768 * 4);   // residual fp32 (t = b*197+l)
  bf16*  ybf  = (bf16*) alloc(6400ull * 768 * 2);   // LN out bf16 (plain OR b*200+l padded)
  bf16*  ct   = (bf16*) alloc(2304ull * 6400 * 2);  // QKV^T, cols b*200+l
  bf16*  ob   = (bf16*) alloc(6400ull * 768 * 2);   // attention out bf16
  bf16*  f1   = (bf16*) alloc(6400ull * 3072 * 2);  // FC1 out bf16
  float* pos  = (float*)alloc(197ull * 768 * 4);
  bf16* wprojB = (bf16*)alloc(768ull * 768 * 2);
  bf16* wqkvB  = (bf16*)alloc(2304ull * 768 * 2);
  bf16* woB    = (bf16*)alloc(768ull * 768 * 2);
  bf16* wfc1B  = (bf16*)alloc(3072ull * 768 * 2);
  bf16* wfc2B  = (bf16*)alloc(768ull * 3072 * 2);
  bf16* whB    = (bf16*)alloc(768ull * 768 * 2);
  bf16* wcB    = (bf16*)alloc(1024ull * 768 * 2);   // rows 1000..1023 poison (finite)
  bf16* repB   = (bf16*)alloc(128ull * 768 * 2);    // rows 32..127 poison
  bf16* hidB   = (bf16*)alloc(128ull * 768 * 2);
  bf16* patches = f1;   // alias: patches dead before FC1 first writes f1

  f2b_k<<<(768 * 768 + 255) / 256, 256, 0, stream>>>(w_proj, wprojB, 768 * 768);
  f2b_k<<<(2304 * 768 + 255) / 256, 256, 0, stream>>>(w_qkv, wqkvB, 2304 * 768);
  f2b_k<<<(768 * 768 + 255) / 256, 256, 0, stream>>>(w_o, woB, 768 * 768);
  f2b_k<<<(3072 * 768 + 255) / 256, 256, 0, stream>>>(w_fc1, wfc1B, 3072 * 768);
  f2b_k<<<(768 * 3072 + 255) / 256, 256, 0, stream>>>(w_fc2, wfc2B, 768 * 3072);
  f2b_k<<<(768 * 768 + 255) / 256, 256, 0, stream>>>(w_h, whB, 768 * 768);
  f2b_k<<<(1000 * 768 + 255) / 256, 256, 0, stream>>>(w_c, wcB, 1000 * 768);
  posenc_k<<<197, 256, 0, stream>>>(pos);
  patchify_k<<<6272 * 768 / 256, 256, 0, stream>>>(x, patches);
  gemm2<64, 0, true><<<49 * 12, 256, 0, stream>>>(patches, wprojB, 6272, 768, 768, 768, 49, 0,
                                                  b_proj, pos, h, nullptr);
  cls_k<<<32, 256, 0, stream>>>(h, pos, cls);

  for (int layer = 0; layer < 12; ++layer) {
    ln4_k<1><<<1576, 256, 0, stream>>>(h, ln1g, ln1b, ybf, 6304, 768);
    // QKV^T: A = w_qkv [2304][768] (small, L2-resident; x-fastest), B = ybf padded 6400
    gemm2<256, 1, false><<<18 * 25, 256, 0, stream>>>(wqkvB, ybf, 2304, 6400, 768, 6400, 18, 1,
                                                      b_qkv, nullptr, nullptr, ct);
    attn_k<<<384, 512, 0, stream>>>(ct, ob);
    gemm2<64, 2, true><<<50 * 12, 256, 0, stream>>>(ob, woB, 6304, 768, 768, 768, 50, 0,
                                                    b_o, nullptr, h, nullptr);
    ln4_k<0><<<1576, 256, 0, stream>>>(h, ln2g, ln2b, ybf, 6304, 768);
    // FC1: A = ybf [6400][768] (big; y-fastest keeps wfc1 L2-resident)
    gemm2<256, 3, false><<<50 * 12, 256, 0, stream>>>(ybf, wfc1B, 6304, 3072, 768, 3072, 50, 0,
                                                      b_fc1, nullptr, nullptr, f1);
    gemm2<64, 2, true><<<50 * 12, 256, 0, stream>>>(f1, wfc2B, 6304, 768, 3072, 768, 50, 0,
                                                    b_fc2, nullptr, h, nullptr);
  }

  ln4_k<0><<<8, 256, 0, stream>>>(h, lnfg, lnfb, repB, 32, 197 * 768);
  gemm2<64, 4, true><<<1 * 12, 256, 0, stream>>>(repB, whB, 32, 768, 768, 768, 1, 0,
                                                 b_h, nullptr, nullptr, hidB);
  gemm2<64, 5, true><<<1 * 16, 256, 0, stream>>>(hidB, wcB, 32, 1000, 768, 1000, 1, 0,
                                                 b_c, nullptr, out, nullptr);
}

// Round 8
// 2922.157 us; speedup vs baseline: 1.1289x; 1.0043x over previous
//
#include <hip/hip_runtime.h>
#include <hip/hip_bf16.h>

// ViT forward, MI355X gfx950. Round 8: counted-vmcnt double-buffered K-loop (T4) for all
// GEMMs — stage(next) -> s_waitcnt vmcnt(8) -> s_barrier -> MFMA -> s_barrier; next-tile
// loads stay in flight across the barrier (never vmcnt(0) in-loop). BN=128 for QKV/FC1.

typedef __bf16 bf16;
typedef __bf16 bf16x8 __attribute__((ext_vector_type(8)));
typedef __bf16 bf16x4 __attribute__((ext_vector_type(4)));
typedef float  f32x4  __attribute__((ext_vector_type(4)));

typedef __attribute__((address_space(1))) const unsigned int gu32;
typedef __attribute__((address_space(3))) unsigned int lu32;

static __device__ __forceinline__ f32x4 mfma_bf16(bf16x8 a, bf16x8 b, f32x4 c) {
  return __builtin_amdgcn_mfma_f32_16x16x32_bf16(a, b, c, 0, 0, 0);
}
static __device__ __forceinline__ void gll16(const bf16* g, bf16* l) {
  __builtin_amdgcn_global_load_lds((gu32*)g, (lu32*)l, 16, 0, 0);
}

// ---------------- small setup kernels ----------------

__global__ __launch_bounds__(256) void f2b_k(const float* __restrict__ a, bf16* __restrict__ o, int n) {
  int i = blockIdx.x * 256 + threadIdx.x;
  if (i < n) o[i] = (bf16)a[i];
}

__global__ __launch_bounds__(256) void posenc_k(float* __restrict__ pos) {
  int l = blockIdx.x;
  for (int d = threadIdx.x; d < 768; d += 256) {
    int ieff = d & ~1;
    float ang = (float)l * expf(-(float)ieff * (9.210340371976184f / 768.0f)); // 10000^{-i/768}
    pos[l * 768 + d] = (d & 1) ? cosf(ang) : sinf(ang);
  }
}

// patches[t, c*256+i*16+j] = x[b, c, ph*16+i, pw*16+j],  t = b*196 + ph*14 + pw
__global__ __launch_bounds__(256) void patchify_k(const float* __restrict__ x, bf16* __restrict__ p) {
  int idx = blockIdx.x * 256 + threadIdx.x;     // 6272*768 exact
  int t = idx / 768, col = idx - t * 768;
  int b = t / 196, pp = t - b * 196;
  int ph = pp / 14, pw = pp - ph * 14;
  int c = col >> 8, r = col & 255, i = r >> 4, j = r & 15;
  p[idx] = (bf16)x[((b * 3 + c) * 224 + ph * 16 + i) * 224 + pw * 16 + j];
}

// CLS row: h[b*197+0, :] = cls + pos[0]
__global__ __launch_bounds__(256) void cls_k(float* __restrict__ h, const float* __restrict__ pos,
                                             const float* __restrict__ cls) {
  int b = blockIdx.x;
  for (int d = threadIdx.x; d < 768; d += 256)
    h[((size_t)b * 197) * 768 + d] = cls[d] + pos[d];
}

// LayerNorm over 768, one wave per row, 4 rows/block, bf16 out.
// PAD=1: output row index remapped t=b*197+l -> b*200+l (QKV-GEMM B operand layout).
template<int PAD>
__global__ __launch_bounds__(256) void ln4_k(const float* __restrict__ x, const float* __restrict__ g,
                                             const float* __restrict__ bb, bf16* __restrict__ y,
                                             int nrows, int instride) {
  const int wave = threadIdx.x >> 6, lane = threadIdx.x & 63;
  const int row = blockIdx.x * 4 + wave;
  if (row >= nrows) return;
  const float4* x4 = (const float4*)(x + (size_t)row * instride);
  float4 v0 = x4[lane], v1 = x4[lane + 64], v2 = x4[lane + 128];
  float s  = v0.x + v0.y + v0.z + v0.w + v1.x + v1.y + v1.z + v1.w + v2.x + v2.y + v2.z + v2.w;
  float s2 = v0.x*v0.x + v0.y*v0.y + v0.z*v0.z + v0.w*v0.w
           + v1.x*v1.x + v1.y*v1.y + v1.z*v1.z + v1.w*v1.w
           + v2.x*v2.x + v2.y*v2.y + v2.z*v2.z + v2.w*v2.w;
  #pragma unroll
  for (int o = 1; o < 64; o <<= 1) { s += __shfl_xor(s, o); s2 += __shfl_xor(s2, o); }
  float m = s * (1.0f / 768.0f);
  float inv = rsqrtf(s2 * (1.0f / 768.0f) - m * m + 1e-5f);
  int orow = row;
  if (PAD) { int bq = row / 197; orow = row + bq * 3; }
  bf16* yr = y + (size_t)orow * 768;
  const float4* g4 = (const float4*)g;
  const float4* b4 = (const float4*)bb;
  #pragma unroll
  for (int i = 0; i < 3; ++i) {
    int idx = lane + i * 64;
    float4 vv = (i == 0) ? v0 : (i == 1) ? v1 : v2;
    float4 gv = g4[idx], bv = b4[idx];
    bf16x4 o;
    o[0] = (bf16)((vv.x - m) * inv * gv.x + bv.x);
    o[1] = (bf16)((vv.y - m) * inv * gv.y + bv.y);
    o[2] = (bf16)((vv.z - m) * inv * gv.z + bv.z);
    o[3] = (bf16)((vv.w - m) * inv * gv.w + bv.w);
    *(bf16x4*)(yr + idx * 4) = o;
  }
}

// ---------------- NT GEMM, counted-vmcnt 2-deep pipeline ----------------
// C[M,N] = A[M,K] * B[N,K]^T. 128xBN tile, BK=64, 4 waves (2x2), double-buffered.
// Per K-step: stage(next)->vmcnt(LPI)->barrier->MFMA->barrier. Loads fly across barriers.
// 1D grid + bijective XCD chunk swizzle; xfast: chunk-internal order for L2 reuse.
// EPI: 0=PROJ (h row remap + pos add, fp32)  1=QKVT (bf16, bias by ROW, rows<768 *0.125)
//      2=ACCUM (outF[t*768+col]+=) 3=FC1 gelu (bf16, stride 3072)
//      4=TANH (bf16, stride 768)   5=GUARDED fp32 store (stride ldc, col<N)
template<int BN, int EPI>
__global__ __launch_bounds__(256, 2) void gemm2(
    const bf16* __restrict__ A, const bf16* __restrict__ B,
    int M, int N, int K, int ldc, int gx, int xfast, const float* __restrict__ bias,
    const float* __restrict__ posw,
    float* __restrict__ outF, bf16* __restrict__ outB)
{
  constexpr int WN = (BN == 128) ? 64 : 32;
  constexpr int NI = WN / 16;
  constexpr int NB = BN / 32;                 // B stage shots per wave
  __shared__ alignas(16) bf16 As[2][128 * 64];
  __shared__ alignas(16) bf16 Bs[2][BN * 64];
  const int tid = threadIdx.x;
  const int lane = tid & 63, wave = tid >> 6;
  const int wr = wave >> 1, wc = wave & 1;
  const int lrow = lane & 15, lgrp = lane >> 4;

  // bijective XCD chunk swizzle (m204)
  const int nwg = gridDim.x, bid0 = blockIdx.x;
  const int xcd = bid0 & 7, loc = bid0 >> 3;
  const int q = nwg >> 3, r = nwg & 7;
  const int nb = (xcd < r ? xcd * (q + 1) : r * (q + 1) + (xcd - r) * q) + loc;
  int bx, by;
  if (xfast) { bx = nb % gx; by = nb / gx; }
  else       { int gy = nwg / gx; by = nb % gy; bx = nb / gy; }
  const int row0 = bx * 128, col0 = by * BN;

  f32x4 acc[4][NI] = {};
  const int srow = lane >> 3, schunk = lane & 7;
  const int nk = K >> 6;

  // strength-reduced staging pointers (advance by 64 elements per K-step)
  const bf16* aptr[4];
  const bf16* bptr[NB];
  {
    const bf16* Agb = A + (size_t)row0 * K;
    const bf16* Bgb = B + (size_t)col0 * K;
    #pragma unroll
    for (int i = 0; i < 4; ++i) {
      int rr = (wave * 4 + i) * 8 + srow;
      aptr[i] = Agb + (size_t)rr * K + ((schunk ^ (rr & 7)) << 3);
    }
    #pragma unroll
    for (int i = 0; i < NB; ++i) {
      int rr = (wave * NB + i) * 8 + srow;
      bptr[i] = Bgb + (size_t)rr * K + ((schunk ^ (rr & 7)) << 3);
    }
  }
  // precomputed LDS element offsets (loop-invariant)
  int aoff[2][4], boff[2][NI];
  #pragma unroll
  for (int kk = 0; kk < 2; ++kk) {
    #pragma unroll
    for (int mi = 0; mi < 4; ++mi) {
      int rr = wr * 64 + mi * 16 + lrow;
      aoff[kk][mi] = rr * 64 + (((kk * 4 + lgrp) ^ (rr & 7)) << 3);
    }
    #pragma unroll
    for (int ni = 0; ni < NI; ++ni) {
      int rr = wc * WN + ni * 16 + lrow;
      boff[kk][ni] = rr * 64 + (((kk * 4 + lgrp) ^ (rr & 7)) << 3);
    }
  }

  auto stage = [&](int buf) {
    #pragma unroll
    for (int i = 0; i < 4; ++i) {
      gll16(aptr[i], As[buf] + (wave * 4 + i) * 512);
      aptr[i] += 64;
    }
    #pragma unroll
    for (int i = 0; i < NB; ++i) {
      gll16(bptr[i], Bs[buf] + (wave * NB + i) * 512);
      bptr[i] += 64;
    }
  };
  auto compute = [&](const bf16* Ac, const bf16* Bc) {
    #pragma unroll
    for (int kk = 0; kk < 2; ++kk) {
      bf16x8 af[4], bfr[NI];
      #pragma unroll
      for (int mi = 0; mi < 4; ++mi) af[mi] = *(const bf16x8*)(Ac + aoff[kk][mi]);
      #pragma unroll
      for (int ni = 0; ni < NI; ++ni) bfr[ni] = *(const bf16x8*)(Bc + boff[kk][ni]);
      __builtin_amdgcn_s_setprio(1);
      #pragma unroll
      for (int mi = 0; mi < 4; ++mi)
        #pragma unroll
        for (int ni = 0; ni < NI; ++ni)
          acc[mi][ni] = mfma_bf16(af[mi], bfr[ni], acc[mi][ni]);
      __builtin_amdgcn_s_setprio(0);
    }
  };

  stage(0);                                   // prologue: tile 0 -> buf 0
  int cur = 0;
  for (int kt = 0; kt < nk; ++kt) {
    if (kt + 1 < nk) {
      stage(cur ^ 1);                         // issue next tile; stays in flight
      if constexpr (BN == 128) asm volatile("s_waitcnt vmcnt(8)" ::: "memory");
      else                     asm volatile("s_waitcnt vmcnt(6)" ::: "memory");
    } else {
      asm volatile("s_waitcnt vmcnt(0)" ::: "memory");
    }
    __builtin_amdgcn_sched_barrier(0);
    __builtin_amdgcn_s_barrier();             // current tile fully in LDS (all waves)
    compute(As[cur], Bs[cur]);
    __builtin_amdgcn_s_barrier();             // all reads done before overwrite
    cur ^= 1;
  }

  // epilogue: C frag layout col = lane&15, row = (lane>>4)*4 + j
  #pragma unroll
  for (int ni = 0; ni < NI; ++ni) {
    const int col = col0 + wc * WN + ni * 16 + lrow;
    float bs = 0.0f;
    if (EPI != 1) {
      if (EPI == 5) bs = (col < N) ? bias[col] : 0.0f;
      else          bs = bias[col];
    }
    #pragma unroll
    for (int mi = 0; mi < 4; ++mi) {
      const int rbase = row0 + wr * 64 + mi * 16 + (lgrp << 2);
      #pragma unroll
      for (int j = 0; j < 4; ++j) {
        const int t = rbase + j;
        if (EPI == 1) {
          float val = acc[mi][ni][j] + bias[t];
          if (t < 768) val *= 0.125f;
          outB[(size_t)t * ldc + col] = (bf16)val;
        } else {
          if (t >= M) continue;
          float val = acc[mi][ni][j] + bs;
          if (EPI == 0) {
            int b = t / 196, p = t - b * 196;
            outF[((size_t)(b * 197 + 1 + p)) * 768 + col] = val + posw[(size_t)(1 + p) * 768 + col];
          } else if (EPI == 2) {
            outF[(size_t)t * 768 + col] += val;
          } else if (EPI == 3) {
            outB[(size_t)t * 3072 + col] = (bf16)(0.5f * val * (1.0f + erff(val * 0.70710678118654752f)));
          } else if (EPI == 4) {
            outB[(size_t)t * 768 + col] = (bf16)tanhf(val);
          } else {
            if (col < N) outF[(size_t)t * ldc + col] = val;
          }
        }
      }
    }
  }
}

// ---------------- attention: one block per (b, head), 8 waves ----------------
// Ct: QKV^T [2304][6400] bf16, cols = b*200 + l (rows n = comp*768 + d*12 + h; Q pre-scaled 1/8).
// O: [6304][768] bf16 (t = b*197 + l).
__global__ __launch_bounds__(512) void attn_k(const bf16* __restrict__ Ct, bf16* __restrict__ O) {
  __shared__ alignas(16) bf16 Ks[208 * 64];       // [l][d] XOR-swizzled
  __shared__ alignas(16) bf16 Qs[208 * 64];       // [l][d] XOR-swizzled
  __shared__ alignas(16) bf16 Vs[64 * 232];       // [d][l] pad 232, cols 197..231 zeroed
  __shared__ alignas(16) bf16 Ps[8][16 * 232];    // per-wave P tile
  const int bh = blockIdx.x;
  const int b = bh / 12, hh = bh - b * 12;
  const int tid = threadIdx.x, lane = tid & 63, wave = tid >> 6;
  const int lrow = lane & 15, lgrp = lane >> 4;
  const size_t tc0 = (size_t)b * 200;

  for (int task = tid; task < 1600; task += 512) {
    int d = task / 25, lc = task - d * 25;
    int l0 = lc * 8;
    const size_t cb = tc0 + l0;
    bf16x8 qv = *(const bf16x8*)(Ct + ((size_t)(d * 12 + hh)) * 6400 + cb);
    bf16x8 kv = *(const bf16x8*)(Ct + ((size_t)(768 + d * 12 + hh)) * 6400 + cb);
    bf16x8 vv = *(const bf16x8*)(Ct + ((size_t)(1536 + d * 12 + hh)) * 6400 + cb);
    #pragma unroll
    for (int e = 0; e < 8; ++e) {
      int l = l0 + e;
      int sw = ((((d >> 3) ^ (l & 7)) << 3) | (d & 7));
      Ks[l * 64 + sw] = kv[e];
      Qs[l * 64 + sw] = qv[e];
    }
    *(bf16x8*)(Vs + d * 232 + l0) = vv;
  }
  for (int q = tid; q < 64 * 35; q += 512) {      // zero V cols 197..231
    int d = q / 35, c = 197 + (q - d * 35);
    Vs[d * 232 + c] = (bf16)0.0f;
  }
  __syncthreads();

  for (int rt = wave; rt < 13; rt += 8) {
    const int r = rt * 16 + lrow;
    bf16x8 a0 = *(const bf16x8*)(Qs + r * 64 + ((lgrp ^ (r & 7)) << 3));
    bf16x8 a1 = *(const bf16x8*)(Qs + r * 64 + (((4 + lgrp) ^ (r & 7)) << 3));
    f32x4 sacc[13];
    #pragma unroll
    for (int ct = 0; ct < 13; ++ct) {
      const int kr = ct * 16 + lrow;
      bf16x8 b0 = *(const bf16x8*)(Ks + kr * 64 + ((lgrp ^ (kr & 7)) << 3));
      bf16x8 b1 = *(const bf16x8*)(Ks + kr * 64 + (((4 + lgrp) ^ (kr & 7)) << 3));
      f32x4 s = {};
      s = mfma_bf16(a0, b0, s);
      s = mfma_bf16(a1, b1, s);
      sacc[ct] = s;
    }
    bf16* Pw = Ps[wave];
    float inv4[4];
    #pragma unroll
    for (int j = 0; j < 4; ++j) {
      const int prow = (lgrp << 2) + j;
      float mx = -3.0e38f;
      #pragma unroll
      for (int ct = 0; ct < 13; ++ct) {
        int c = ct * 16 + lrow;
        if (c < 197) mx = fmaxf(mx, sacc[ct][j]);
      }
      #pragma unroll
      for (int o = 1; o < 16; o <<= 1) mx = fmaxf(mx, __shfl_xor(mx, o));
      float sum = 0.0f;
      #pragma unroll
      for (int ct = 0; ct < 13; ++ct) {
        int c = ct * 16 + lrow;
        float p = (c < 197) ? __expf(sacc[ct][j] - mx) : 0.0f;
        sum += p;
        Pw[prow * 232 + c] = (bf16)p;
      }
      #pragma unroll
      for (int o = 1; o < 16; o <<= 1) sum += __shfl_xor(sum, o);
      inv4[j] = 1.0f / sum;
      Pw[prow * 232 + 208 + lrow] = (bf16)0.0f;   // zero P cols 208..223
    }
    f32x4 oacc[4] = {};
    #pragma unroll
    for (int mc = 0; mc < 7; ++mc) {              // K-dim 224
      bf16x8 pa = *(const bf16x8*)(Pw + lrow * 232 + mc * 32 + (lgrp << 3));
      #pragma unroll
      for (int n2 = 0; n2 < 4; ++n2) {
        bf16x8 vb = *(const bf16x8*)(Vs + (n2 * 16 + lrow) * 232 + mc * 32 + (lgrp << 3));
        oacc[n2] = mfma_bf16(pa, vb, oacc[n2]);
      }
    }
    #pragma unroll
    for (int n2 = 0; n2 < 4; ++n2) {
      const int d = n2 * 16 + lrow;
      #pragma unroll
      for (int j = 0; j < 4; ++j) {
        const int qrow = rt * 16 + (lgrp << 2) + j;
        if (qrow < 197)
          O[((size_t)b * 197 + qrow) * 768 + hh * 64 + d] = (bf16)(oacc[n2][j] * inv4[j]);
      }
    }
  }
}

// ---------------- driver ----------------

extern "C" void kernel_launch(void* const* d_in, const int* in_sizes, int n_in,
                              void* d_out, int out_size, void* d_ws, size_t ws_size,
                              hipStream_t stream) {
  const float* x      = (const float*)d_in[0];
  const float* w_proj = (const float*)d_in[1];
  const float* b_proj = (const float*)d_in[2];
  const float* cls    = (const float*)d_in[3];
  const float* ln1g   = (const float*)d_in[4];
  const float* ln1b   = (const float*)d_in[5];
  const float* w_qkv  = (const float*)d_in[6];
  const float* b_qkv  = (const float*)d_in[7];
  const float* w_o    = (const float*)d_in[8];
  const float* b_o    = (const float*)d_in[9];
  const float* ln2g   = (const float*)d_in[10];
  const float* ln2b   = (const float*)d_in[11];
  const float* w_fc1  = (const float*)d_in[12];
  const float* b_fc1  = (const float*)d_in[13];
  const float* w_fc2  = (const float*)d_in[14];
  const float* b_fc2  = (const float*)d_in[15];
  const float* lnfg   = (const float*)d_in[16];
  const float* lnfb   = (const float*)d_in[17];
  const float* w_h    = (const float*)d_in[18];
  const float* b_h    = (const float*)d_in[19];
  const float* w_c    = (const float*)d_in[20];
  const float* b_c    = (const float*)d_in[21];
  float* out = (float*)d_out;

  uint8_t* ws = (uint8_t*)d_ws;
  size_t off = 0;
  auto alloc = [&](size_t bytes) -> void* {
    void* p = ws + off; off += (bytes + 255) & ~(size_t)255; return p;
  };
  float* h    = (float*)alloc(6400ull * 768 * 4);   // residual fp32 (t = b*197+l)
  bf16*  ybf  = (bf16*) alloc(6400ull * 768 * 2);   // LN out bf16 (plain OR b*200+l padded)
  bf16*  ct   = (bf16*) alloc(2304ull * 6400 * 2);  // QKV^T, cols b*200+l
  bf16*  ob   = (bf16*) alloc(6400ull * 768 * 2);   // attention out bf16
  bf16*  f1   = (bf16*) alloc(6400ull * 3072 * 2);  // FC1 out bf16
  float* pos  = (float*)alloc(197ull * 768 * 4);
  bf16* wprojB = (bf16*)alloc(768ull * 768 * 2);
  bf16* wqkvB  = (bf16*)alloc(2304ull * 768 * 2);
  bf16* woB    = (bf16*)alloc(768ull * 768 * 2);
  bf16* wfc1B  = (bf16*)alloc(3072ull * 768 * 2);
  bf16* wfc2B  = (bf16*)alloc(768ull * 3072 * 2);
  bf16* whB    = (bf16*)alloc(768ull * 768 * 2);
  bf16* wcB    = (bf16*)alloc(1024ull * 768 * 2);   // rows 1000..1023 poison (finite)
  bf16* repB   = (bf16*)alloc(128ull * 768 * 2);    // rows 32..127 poison
  bf16* hidB   = (bf16*)alloc(128ull * 768 * 2);
  bf16* patches = f1;   // alias: patches dead before FC1 first writes f1

  f2b_k<<<(768 * 768 + 255) / 256, 256, 0, stream>>>(w_proj, wprojB, 768 * 768);
  f2b_k<<<(2304 * 768 + 255) / 256, 256, 0, stream>>>(w_qkv, wqkvB, 2304 * 768);
  f2b_k<<<(768 * 768 + 255) / 256, 256, 0, stream>>>(w_o, woB, 768 * 768);
  f2b_k<<<(3072 * 768 + 255) / 256, 256, 0, stream>>>(w_fc1, wfc1B, 3072 * 768);
  f2b_k<<<(768 * 3072 + 255) / 256, 256, 0, stream>>>(w_fc2, wfc2B, 768 * 3072);
  f2b_k<<<(768 * 768 + 255) / 256, 256, 0, stream>>>(w_h, whB, 768 * 768);
  f2b_k<<<(1000 * 768 + 255) / 256, 256, 0, stream>>>(w_c, wcB, 1000 * 768);
  posenc_k<<<197, 256, 0, stream>>>(pos);
  patchify_k<<<6272 * 768 / 256, 256, 0, stream>>>(x, patches);
  gemm2<64, 0><<<49 * 12, 256, 0, stream>>>(patches, wprojB, 6272, 768, 768, 768, 49, 0,
                                            b_proj, pos, h, nullptr);
  cls_k<<<32, 256, 0, stream>>>(h, pos, cls);

  for (int layer = 0; layer < 12; ++layer) {
    ln4_k<1><<<1576, 256, 0, stream>>>(h, ln1g, ln1b, ybf, 6304, 768);
    // QKV^T: A = w_qkv [2304][768] (x-fastest: A L2-resident per chunk), B = ybf padded 6400
    gemm2<128, 1><<<18 * 50, 256, 0, stream>>>(wqkvB, ybf, 2304, 6400, 768, 6400, 18, 1,
                                               b_qkv, nullptr, nullptr, ct);
    attn_k<<<384, 512, 0, stream>>>(ct, ob);
    gemm2<64, 2><<<50 * 12, 256, 0, stream>>>(ob, woB, 6304, 768, 768, 768, 50, 0,
                                              b_o, nullptr, h, nullptr);
    ln4_k<0><<<1576, 256, 0, stream>>>(h, ln2g, ln2b, ybf, 6304, 768);
    // FC1: y-fastest keeps w_fc1 panels hot per chunk
    gemm2<128, 3><<<50 * 24, 256, 0, stream>>>(ybf, wfc1B, 6304, 3072, 768, 3072, 50, 0,
                                               b_fc1, nullptr, nullptr, f1);
    gemm2<64, 2><<<50 * 12, 256, 0, stream>>>(f1, wfc2B, 6304, 768, 3072, 768, 50, 0,
                                              b_fc2, nullptr, h, nullptr);
  }

  ln4_k<0><<<8, 256, 0, stream>>>(h, lnfg, lnfb, repB, 32, 197 * 768);
  gemm2<64, 4><<<1 * 12, 256, 0, stream>>>(repB, whB, 32, 768, 768, 768, 1, 0,
                                           b_h, nullptr, nullptr, hidB);
  gemm2<64, 5><<<1 * 16, 256, 0, stream>>>(hidB, wcB, 32, 1000, 768, 1000, 1, 0,
                                           b_c, nullptr, out, nullptr);
}

// Round 9
// 2761.370 us; speedup vs baseline: 1.1947x; 1.0582x over previous
//
#include <hip/hip_runtime.h>
#include <hip/hip_bf16.h>

// ViT forward, MI355X gfx950. Round 9: GEMMs reverted to the proven R3 structure
// (single-buffer, 32 KiB LDS, 3-5 blocks/CU inter-block overlap — every pipelining
// variant R4-R8 was flat-to-negative). Attention rebuilt: 4 waves, 80 KiB LDS exactly
// -> 2 blocks/CU, full 384-block residency; Q preloaded to regs, P overlays Qs.

typedef __bf16 bf16;
typedef __bf16 bf16x8 __attribute__((ext_vector_type(8)));
typedef __bf16 bf16x4 __attribute__((ext_vector_type(4)));
typedef float  f32x4  __attribute__((ext_vector_type(4)));

typedef __attribute__((address_space(1))) const unsigned int gu32;
typedef __attribute__((address_space(3))) unsigned int lu32;

static __device__ __forceinline__ f32x4 mfma_bf16(bf16x8 a, bf16x8 b, f32x4 c) {
  return __builtin_amdgcn_mfma_f32_16x16x32_bf16(a, b, c, 0, 0, 0);
}
static __device__ __forceinline__ void gll16(const bf16* g, bf16* l) {
  __builtin_amdgcn_global_load_lds((gu32*)g, (lu32*)l, 16, 0, 0);
}

// ---------------- small setup kernels ----------------

__global__ __launch_bounds__(256) void f2b_k(const float* __restrict__ a, bf16* __restrict__ o, int n) {
  int i = blockIdx.x * 256 + threadIdx.x;
  if (i < n) o[i] = (bf16)a[i];
}

__global__ __launch_bounds__(256) void posenc_k(float* __restrict__ pos) {
  int l = blockIdx.x;
  for (int d = threadIdx.x; d < 768; d += 256) {
    int ieff = d & ~1;
    float ang = (float)l * expf(-(float)ieff * (9.210340371976184f / 768.0f)); // 10000^{-i/768}
    pos[l * 768 + d] = (d & 1) ? cosf(ang) : sinf(ang);
  }
}

// patches[t, c*256+i*16+j] = x[b, c, ph*16+i, pw*16+j],  t = b*196 + ph*14 + pw
__global__ __launch_bounds__(256) void patchify_k(const float* __restrict__ x, bf16* __restrict__ p) {
  int idx = blockIdx.x * 256 + threadIdx.x;     // 6272*768 exact
  int t = idx / 768, col = idx - t * 768;
  int b = t / 196, pp = t - b * 196;
  int ph = pp / 14, pw = pp - ph * 14;
  int c = col >> 8, r = col & 255, i = r >> 4, j = r & 15;
  p[idx] = (bf16)x[((b * 3 + c) * 224 + ph * 16 + i) * 224 + pw * 16 + j];
}

// CLS row: h[b*197+0, :] = cls + pos[0]
__global__ __launch_bounds__(256) void cls_k(float* __restrict__ h, const float* __restrict__ pos,
                                             const float* __restrict__ cls) {
  int b = blockIdx.x;
  for (int d = threadIdx.x; d < 768; d += 256)
    h[((size_t)b * 197) * 768 + d] = cls[d] + pos[d];
}

// LayerNorm over 768, one wave per row, 4 rows/block, bf16 out.
// PAD=1: output row index remapped t=b*197+l -> b*200+l (QKV-GEMM B operand layout).
template<int PAD>
__global__ __launch_bounds__(256) void ln4_k(const float* __restrict__ x, const float* __restrict__ g,
                                             const float* __restrict__ bb, bf16* __restrict__ y,
                                             int nrows, int instride) {
  const int wave = threadIdx.x >> 6, lane = threadIdx.x & 63;
  const int row = blockIdx.x * 4 + wave;
  if (row >= nrows) return;
  const float4* x4 = (const float4*)(x + (size_t)row * instride);
  float4 v0 = x4[lane], v1 = x4[lane + 64], v2 = x4[lane + 128];
  float s  = v0.x + v0.y + v0.z + v0.w + v1.x + v1.y + v1.z + v1.w + v2.x + v2.y + v2.z + v2.w;
  float s2 = v0.x*v0.x + v0.y*v0.y + v0.z*v0.z + v0.w*v0.w
           + v1.x*v1.x + v1.y*v1.y + v1.z*v1.z + v1.w*v1.w
           + v2.x*v2.x + v2.y*v2.y + v2.z*v2.z + v2.w*v2.w;
  #pragma unroll
  for (int o = 1; o < 64; o <<= 1) { s += __shfl_xor(s, o); s2 += __shfl_xor(s2, o); }
  float m = s * (1.0f / 768.0f);
  float inv = rsqrtf(s2 * (1.0f / 768.0f) - m * m + 1e-5f);
  int orow = row;
  if (PAD) { int bq = row / 197; orow = row + bq * 3; }
  bf16* yr = y + (size_t)orow * 768;
  const float4* g4 = (const float4*)g;
  const float4* b4 = (const float4*)bb;
  #pragma unroll
  for (int i = 0; i < 3; ++i) {
    int idx = lane + i * 64;
    float4 vv = (i == 0) ? v0 : (i == 1) ? v1 : v2;
    float4 gv = g4[idx], bv = b4[idx];
    bf16x4 o;
    o[0] = (bf16)((vv.x - m) * inv * gv.x + bv.x);
    o[1] = (bf16)((vv.y - m) * inv * gv.y + bv.y);
    o[2] = (bf16)((vv.z - m) * inv * gv.z + bv.z);
    o[3] = (bf16)((vv.w - m) * inv * gv.w + bv.w);
    *(bf16x4*)(yr + idx * 4) = o;
  }
}

// ---------------- NT GEMM, R3 structure (single-buffer, 2D grid) ----------------
// C[M,N] = A[M,K] * B[N,K]^T. 128xBN tile, BK=64, 4 waves (2x2).
// EPI: 0=PROJ (h row remap + pos add, fp32)  1=QKVT (bf16, bias by ROW, rows<768 *0.125)
//      2=ACCUM (outF[t*768+col]+=) 3=FC1 gelu (bf16, stride 3072)
//      4=TANH (bf16, stride 768)   5=GUARDED fp32 store (stride ldc, col<N)
template<int BN, int EPI>
__global__ __launch_bounds__(256) void gemm2(
    const bf16* __restrict__ A, const bf16* __restrict__ B,
    int M, int N, int K, int ldc, const float* __restrict__ bias,
    const float* __restrict__ posw,
    float* __restrict__ outF, bf16* __restrict__ outB)
{
  constexpr int WN = (BN == 128) ? 64 : 32;
  constexpr int NI = WN / 16;
  constexpr int NB = BN / 32;
  __shared__ alignas(16) bf16 As[128 * 64];
  __shared__ alignas(16) bf16 Bs[BN * 64];
  const int tid = threadIdx.x;
  const int lane = tid & 63, wave = tid >> 6;
  const int wr = wave >> 1, wc = wave & 1;
  const int lrow = lane & 15, lgrp = lane >> 4;
  const int row0 = blockIdx.x * 128, col0 = blockIdx.y * BN;

  f32x4 acc[4][NI] = {};
  const bf16* Agb = A + (size_t)row0 * K;
  const bf16* Bgb = B + (size_t)col0 * K;
  const int srow = lane >> 3, schunk = lane & 7;
  const int nk = K >> 6;

  for (int kt = 0; kt < nk; ++kt) {
    const bf16* Ag = Agb + kt * 64;
    const bf16* Bg = Bgb + kt * 64;
    #pragma unroll
    for (int i = 0; i < 4; ++i) {
      int rr = (wave * 4 + i) * 8 + srow;
      int g = schunk ^ (rr & 7);
      gll16(Ag + (size_t)rr * K + g * 8, As + (wave * 4 + i) * 512);
    }
    #pragma unroll
    for (int i = 0; i < NB; ++i) {
      int rr = (wave * NB + i) * 8 + srow;
      int g = schunk ^ (rr & 7);
      gll16(Bg + (size_t)rr * K + g * 8, Bs + (wave * NB + i) * 512);
    }
    __syncthreads();
    #pragma unroll
    for (int kk = 0; kk < 2; ++kk) {
      bf16x8 af[4], bfr[NI];
      #pragma unroll
      for (int mi = 0; mi < 4; ++mi) {
        int r = wr * 64 + mi * 16 + lrow;
        af[mi] = *(const bf16x8*)(As + r * 64 + (((kk * 4 + lgrp) ^ (r & 7)) << 3));
      }
      #pragma unroll
      for (int ni = 0; ni < NI; ++ni) {
        int r = wc * WN + ni * 16 + lrow;
        bfr[ni] = *(const bf16x8*)(Bs + r * 64 + (((kk * 4 + lgrp) ^ (r & 7)) << 3));
      }
      #pragma unroll
      for (int mi = 0; mi < 4; ++mi)
        #pragma unroll
        for (int ni = 0; ni < NI; ++ni)
          acc[mi][ni] = mfma_bf16(af[mi], bfr[ni], acc[mi][ni]);
    }
    __syncthreads();
  }

  // epilogue: C frag layout col = lane&15, row = (lane>>4)*4 + j
  #pragma unroll
  for (int ni = 0; ni < NI; ++ni) {
    const int col = col0 + wc * WN + ni * 16 + lrow;
    float bs = 0.0f;
    if (EPI != 1) {
      if (EPI == 5) bs = (col < N) ? bias[col] : 0.0f;
      else          bs = bias[col];
    }
    #pragma unroll
    for (int mi = 0; mi < 4; ++mi) {
      const int rbase = row0 + wr * 64 + mi * 16 + (lgrp << 2);
      #pragma unroll
      for (int j = 0; j < 4; ++j) {
        const int t = rbase + j;
        if (EPI == 1) {
          float val = acc[mi][ni][j] + bias[t];
          if (t < 768) val *= 0.125f;
          outB[(size_t)t * ldc + col] = (bf16)val;
        } else {
          if (t >= M) continue;
          float val = acc[mi][ni][j] + bs;
          if (EPI == 0) {
            int b = t / 196, p = t - b * 196;
            outF[((size_t)(b * 197 + 1 + p)) * 768 + col] = val + posw[(size_t)(1 + p) * 768 + col];
          } else if (EPI == 2) {
            outF[(size_t)t * 768 + col] += val;
          } else if (EPI == 3) {
            outB[(size_t)t * 3072 + col] = (bf16)(0.5f * val * (1.0f + erff(val * 0.70710678118654752f)));
          } else if (EPI == 4) {
            outB[(size_t)t * 768 + col] = (bf16)tanhf(val);
          } else {
            if (col < N) outF[(size_t)t * ldc + col] = val;
          }
        }
      }
    }
  }
}

// ---------------- attention: one block per (b, head), 4 waves, 80 KiB LDS ----------------
// Ct: QKV^T [2304][6400] bf16, cols = b*200 + l (rows n = comp*768 + d*12 + h; Q pre-scaled 1/8).
// O: [6304][768] bf16 (t = b*197 + l).
// LDS: Ks [208][64] swz | QP union: Qs [208][64] swz -> Ps [4][16][216] | Vs [64][216].
// 26624 + 27648 + 27648 = 81920 B exactly -> 2 blocks/CU, all 384 blocks resident.
__global__ __launch_bounds__(256) void attn_k(const bf16* __restrict__ Ct, bf16* __restrict__ O) {
  __shared__ alignas(16) bf16 smem[40960];
  bf16* Ks = smem;              // [208][64] xor-swizzled
  bf16* QP = smem + 13312;      // Qs [208][64] swizzled, later Ps [4][16][216]
  bf16* Vs = smem + 27136;      // [64][216], cols 200..215 zeroed (P=0 masks 197..207 junk)
  const int bh = blockIdx.x;
  const int b = bh / 12, hh = bh - b * 12;
  const int tid = threadIdx.x, lane = tid & 63, wave = tid >> 6;
  const int lrow = lane & 15, lgrp = lane >> 4;
  const size_t tc0 = (size_t)b * 200;

  for (int task = tid; task < 1600; task += 256) {   // 64 d-rows x 25 chunks of 8 tokens
    int d = task / 25, lc = task - d * 25;
    int l0 = lc * 8;
    const size_t cb = tc0 + l0;
    bf16x8 qv = *(const bf16x8*)(Ct + ((size_t)(d * 12 + hh)) * 6400 + cb);
    bf16x8 kv = *(const bf16x8*)(Ct + ((size_t)(768 + d * 12 + hh)) * 6400 + cb);
    bf16x8 vv = *(const bf16x8*)(Ct + ((size_t)(1536 + d * 12 + hh)) * 6400 + cb);
    #pragma unroll
    for (int e = 0; e < 8; ++e) {
      int l = l0 + e;
      int sw = ((((d >> 3) ^ (l & 7)) << 3) | (d & 7));
      Ks[l * 64 + sw] = kv[e];
      QP[l * 64 + sw] = qv[e];
    }
    *(bf16x8*)(Vs + d * 216 + l0) = vv;
  }
  for (int t2 = tid; t2 < 64 * 16; t2 += 256) {      // zero V cols 200..215 (no race)
    int d = t2 >> 4, c = 200 + (t2 & 15);
    Vs[d * 216 + c] = (bf16)0.0f;
  }
  __syncthreads();

  // preload Q fragments for this wave's q-tiles (before Ps overlays Qs)
  bf16x8 qa0[4], qa1[4];
  #pragma unroll
  for (int ii = 0; ii < 4; ++ii) {
    int rt = wave + ii * 4;
    if (rt < 13) {
      int r = rt * 16 + lrow;
      qa0[ii] = *(const bf16x8*)(QP + r * 64 + ((lgrp ^ (r & 7)) << 3));
      qa1[ii] = *(const bf16x8*)(QP + r * 64 + (((4 + lgrp) ^ (r & 7)) << 3));
    }
  }
  __syncthreads();                                    // Q consumed; QP becomes Ps

  bf16* Pw = QP + wave * (16 * 216);
  const bf16x8 zv = {};

  #pragma unroll
  for (int ii = 0; ii < 4; ++ii) {
    const int rt = wave + ii * 4;
    if (rt >= 13) break;
    f32x4 sacc[13];
    #pragma unroll
    for (int ct = 0; ct < 13; ++ct) {
      const int kr = ct * 16 + lrow;
      bf16x8 b0 = *(const bf16x8*)(Ks + kr * 64 + ((lgrp ^ (kr & 7)) << 3));
      bf16x8 b1 = *(const bf16x8*)(Ks + kr * 64 + (((4 + lgrp) ^ (kr & 7)) << 3));
      f32x4 s = {};
      s = mfma_bf16(qa0[ii], b0, s);
      s = mfma_bf16(qa1[ii], b1, s);
      sacc[ct] = s;
    }
    float inv4[4];
    #pragma unroll
    for (int j = 0; j < 4; ++j) {
      const int prow = (lgrp << 2) + j;
      float mx = -3.0e38f;
      #pragma unroll
      for (int ct = 0; ct < 13; ++ct) {
        int c = ct * 16 + lrow;
        if (c < 197) mx = fmaxf(mx, sacc[ct][j]);
      }
      #pragma unroll
      for (int o = 1; o < 16; o <<= 1) mx = fmaxf(mx, __shfl_xor(mx, o));
      float sum = 0.0f;
      #pragma unroll
      for (int ct = 0; ct < 13; ++ct) {
        int c = ct * 16 + lrow;
        float p = (c < 197) ? __expf(sacc[ct][j] - mx) : 0.0f;
        sum += p;
        Pw[prow * 216 + c] = (bf16)p;                // all cols 0..207 written (0 for c>=197)
      }
      #pragma unroll
      for (int o = 1; o < 16; o <<= 1) sum += __shfl_xor(sum, o);
      inv4[j] = 1.0f / sum;
    }
    f32x4 oacc[4] = {};
    #pragma unroll
    for (int mc = 0; mc < 7; ++mc) {                 // K-dim 224; tail k>=16 zeroed in regs
      bf16x8 pa;
      if (mc < 6) {
        pa = *(const bf16x8*)(Pw + lrow * 216 + mc * 32 + (lgrp << 3));
      } else {
        pa = *(const bf16x8*)(Pw + lrow * 216 + 192 + ((lgrp & 1) << 3));
        if (lgrp >= 2) pa = zv;                      // A[k>=16] = 0 -> tail contributes 0
      }
      #pragma unroll
      for (int n2 = 0; n2 < 4; ++n2) {
        const int vr = n2 * 16 + lrow;
        bf16x8 vb;
        if (mc < 6) vb = *(const bf16x8*)(Vs + vr * 216 + mc * 32 + (lgrp << 3));
        else        vb = *(const bf16x8*)(Vs + vr * 216 + 192 + ((lgrp & 1) << 3));
        oacc[n2] = mfma_bf16(pa, vb, oacc[n2]);
      }
    }
    #pragma unroll
    for (int n2 = 0; n2 < 4; ++n2) {
      const int d = n2 * 16 + lrow;
      #pragma unroll
      for (int j = 0; j < 4; ++j) {
        const int qrow = rt * 16 + (lgrp << 2) + j;
        if (qrow < 197)
          O[((size_t)b * 197 + qrow) * 768 + hh * 64 + d] = (bf16)(oacc[n2][j] * inv4[j]);
      }
    }
  }
}

// ---------------- driver ----------------

extern "C" void kernel_launch(void* const* d_in, const int* in_sizes, int n_in,
                              void* d_out, int out_size, void* d_ws, size_t ws_size,
                              hipStream_t stream) {
  const float* x      = (const float*)d_in[0];
  const float* w_proj = (const float*)d_in[1];
  const float* b_proj = (const float*)d_in[2];
  const float* cls    = (const float*)d_in[3];
  const float* ln1g   = (const float*)d_in[4];
  const float* ln1b   = (const float*)d_in[5];
  const float* w_qkv  = (const float*)d_in[6];
  const float* b_qkv  = (const float*)d_in[7];
  const float* w_o    = (const float*)d_in[8];
  const float* b_o    = (const float*)d_in[9];
  const float* ln2g   = (const float*)d_in[10];
  const float* ln2b   = (const float*)d_in[11];
  const float* w_fc1  = (const float*)d_in[12];
  const float* b_fc1  = (const float*)d_in[13];
  const float* w_fc2  = (const float*)d_in[14];
  const float* b_fc2  = (const float*)d_in[15];
  const float* lnfg   = (const float*)d_in[16];
  const float* lnfb   = (const float*)d_in[17];
  const float* w_h    = (const float*)d_in[18];
  const float* b_h    = (const float*)d_in[19];
  const float* w_c    = (const float*)d_in[20];
  const float* b_c    = (const float*)d_in[21];
  float* out = (float*)d_out;

  uint8_t* ws = (uint8_t*)d_ws;
  size_t off = 0;
  auto alloc = [&](size_t bytes) -> void* {
    void* p = ws + off; off += (bytes + 255) & ~(size_t)255; return p;
  };
  float* h    = (float*)alloc(6400ull * 768 * 4);   // residual fp32 (t = b*197+l)
  bf16*  ybf  = (bf16*) alloc(6400ull * 768 * 2);   // LN out bf16 (plain OR b*200+l padded)
  bf16*  ct   = (bf16*) alloc(2304ull * 6400 * 2);  // QKV^T, cols b*200+l
  bf16*  ob   = (bf16*) alloc(6400ull * 768 * 2);   // attention out bf16
  bf16*  f1   = (bf16*) alloc(6400ull * 3072 * 2);  // FC1 out bf16
  float* pos  = (float*)alloc(197ull * 768 * 4);
  bf16* wprojB = (bf16*)alloc(768ull * 768 * 2);
  bf16* wqkvB  = (bf16*)alloc(2304ull * 768 * 2);
  bf16* woB    = (bf16*)alloc(768ull * 768 * 2);
  bf16* wfc1B  = (bf16*)alloc(3072ull * 768 * 2);
  bf16* wfc2B  = (bf16*)alloc(768ull * 3072 * 2);
  bf16* whB    = (bf16*)alloc(768ull * 768 * 2);
  bf16* wcB    = (bf16*)alloc(1024ull * 768 * 2);   // rows 1000..1023 poison (finite)
  bf16* repB   = (bf16*)alloc(128ull * 768 * 2);    // rows 32..127 poison
  bf16* hidB   = (bf16*)alloc(128ull * 768 * 2);
  bf16* patches = f1;   // alias: patches dead before FC1 first writes f1

  f2b_k<<<(768 * 768 + 255) / 256, 256, 0, stream>>>(w_proj, wprojB, 768 * 768);
  f2b_k<<<(2304 * 768 + 255) / 256, 256, 0, stream>>>(w_qkv, wqkvB, 2304 * 768);
  f2b_k<<<(768 * 768 + 255) / 256, 256, 0, stream>>>(w_o, woB, 768 * 768);
  f2b_k<<<(3072 * 768 + 255) / 256, 256, 0, stream>>>(w_fc1, wfc1B, 3072 * 768);
  f2b_k<<<(768 * 3072 + 255) / 256, 256, 0, stream>>>(w_fc2, wfc2B, 768 * 3072);
  f2b_k<<<(768 * 768 + 255) / 256, 256, 0, stream>>>(w_h, whB, 768 * 768);
  f2b_k<<<(1000 * 768 + 255) / 256, 256, 0, stream>>>(w_c, wcB, 1000 * 768);
  posenc_k<<<197, 256, 0, stream>>>(pos);
  patchify_k<<<6272 * 768 / 256, 256, 0, stream>>>(x, patches);
  gemm2<64, 0><<<dim3(49, 12), 256, 0, stream>>>(patches, wprojB, 6272, 768, 768, 768,
                                                 b_proj, pos, h, nullptr);
  cls_k<<<32, 256, 0, stream>>>(h, pos, cls);

  for (int layer = 0; layer < 12; ++layer) {
    ln4_k<1><<<1576, 256, 0, stream>>>(h, ln1g, ln1b, ybf, 6304, 768);
    // QKV^T: A = w_qkv [2304][768], B = ybf (padded rows, 6400) -> Ct [2304][6400]
    gemm2<128, 1><<<dim3(18, 50), 256, 0, stream>>>(wqkvB, ybf, 2304, 6400, 768, 6400,
                                                    b_qkv, nullptr, nullptr, ct);
    attn_k<<<384, 256, 0, stream>>>(ct, ob);
    gemm2<64, 2><<<dim3(50, 12), 256, 0, stream>>>(ob, woB, 6304, 768, 768, 768,
                                                   b_o, nullptr, h, nullptr);
    ln4_k<0><<<1576, 256, 0, stream>>>(h, ln2g, ln2b, ybf, 6304, 768);
    gemm2<128, 3><<<dim3(50, 24), 256, 0, stream>>>(ybf, wfc1B, 6304, 3072, 768, 3072,
                                                    b_fc1, nullptr, nullptr, f1);
    gemm2<64, 2><<<dim3(50, 12), 256, 0, stream>>>(f1, wfc2B, 6304, 768, 3072, 768,
                                                   b_fc2, nullptr, h, nullptr);
  }

  ln4_k<0><<<8, 256, 0, stream>>>(h, lnfg, lnfb, repB, 32, 197 * 768);
  gemm2<64, 4><<<dim3(1, 12), 256, 0, stream>>>(repB, whB, 32, 768, 768, 768,
                                                b_h, nullptr, nullptr, hidB);
  gemm2<64, 5><<<dim3(1, 16), 256, 0, stream>>>(hidB, wcB, 32, 1000, 768, 1000,
                                                b_c, nullptr, out, nullptr);
}